// Round 4
// baseline (222.740 us; speedup 1.0000x reference)
//
#include <hip/hip_runtime.h>
#include <hip/hip_bf16.h>
#include <math.h>
#include <stdint.h>

#define NB 4
#define NS 2048
#define ND 512
#define NH 8
#define DEP 64
#define KVHALF (NS / 2)
#define NT (KVHALF / 64)  // 16 kv tiles per half

typedef __attribute__((ext_vector_type(8))) short bf16x8;
typedef __attribute__((ext_vector_type(4))) short bf16x4;
typedef __attribute__((ext_vector_type(4))) float f32x4;
typedef __attribute__((ext_vector_type(16))) float f32x16;

#define QSCALE 0.18033688011112042f  // DEPTH^-0.5 * log2(e): softmax in exp2

__device__ __forceinline__ short f2b(float f) {
  unsigned u = __float_as_uint(f);
  u += 0x7FFF + ((u >> 16) & 1);  // RNE
  return (short)(u >> 16);
}
__device__ __forceinline__ unsigned pk2(float a, float b) {
  union { __hip_bfloat162 h; unsigned u; } c;
  c.h = __float22bfloat162_rn(float2{a, b});
  return c.u;
}
// async 16B global->LDS DMA; LDS dest is wave-uniform base + lane*16
__device__ __forceinline__ void dma16(const void* g, void* l) {
  __builtin_amdgcn_global_load_lds(
      (const __attribute__((address_space(1))) void*)g,
      (__attribute__((address_space(3))) void*)l, 16, 0, 0);
}

// ---------------------------------------------------------------------------
// prep: one launch does BOTH input casts and all 4 weight transposes.
// grid (4096, 3): y=0 cast x, y=1 cast y, y=2 (x<256) transpose W0..W3.
// ---------------------------------------------------------------------------
__global__ __launch_bounds__(256) void prep(
    const float* __restrict__ x, const float* __restrict__ y,
    const float* __restrict__ W0, const float* __restrict__ W1,
    const float* __restrict__ W2, const float* __restrict__ W3,
    short* __restrict__ xb, short* __restrict__ yb, short* __restrict__ T0,
    short* __restrict__ T1, short* __restrict__ T2, short* __restrict__ T3) {
  const int t = threadIdx.x;
  if (blockIdx.y < 2) {
    const float* src = blockIdx.y ? y : x;
    short* dst = blockIdx.y ? yb : xb;
    size_t i = ((size_t)blockIdx.x * 256 + t) * 4;
    float4 v = *(const float4*)(src + i);
    bf16x4 o;
    o[0] = f2b(v.x); o[1] = f2b(v.y); o[2] = f2b(v.z); o[3] = f2b(v.w);
    *(bf16x4*)(dst + i) = o;
    return;
  }
  const int bx = blockIdx.x;
  if (bx >= 256) return;
  const int wj = bx >> 6, rem = bx & 63;
  const float* W = wj == 0 ? W0 : wj == 1 ? W1 : wj == 2 ? W2 : W3;
  short* T = wj == 0 ? T0 : wj == 1 ? T1 : wj == 2 ? T2 : T3;
  __shared__ float tile[64][65];
  const int k0 = (rem >> 3) * 64, n0 = (rem & 7) * 64;
#pragma unroll
  for (int i = 0; i < 4; ++i) {
    int r = (t >> 4) + i * 16;
    int c = (t & 15) * 4;
    float4 v = *(const float4*)&W[(size_t)(k0 + r) * ND + n0 + c];
    tile[r][c] = v.x; tile[r][c + 1] = v.y;
    tile[r][c + 2] = v.z; tile[r][c + 3] = v.w;
  }
  __syncthreads();
#pragma unroll
  for (int i = 0; i < 4; ++i) {
    int n = (t >> 4) + i * 16;
    int kc = (t & 15) * 4;
    bf16x4 o;
#pragma unroll
    for (int j = 0; j < 4; ++j) o[j] = f2b(tile[kc + j][n]);
    *(bf16x4*)&T[(size_t)(n0 + n) * ND + k0 + kc] = o;
  }
}

// ---------------------------------------------------------------------------
// QKV GEMM: 128x128 tile, 4 waves each 64x64 (acc 4x4), BK=64, single-buffer
// DMA staging (m97 2-barrier), XOR-swizzled LDS (pitch 64, chunk ^= row&7).
// mode 1: bf16 row-major out; 2: bf16 V^T out.
// ---------------------------------------------------------------------------
__device__ __forceinline__ void gemm128(const short* __restrict__ A,
                                        const short* __restrict__ Bt,
                                        short* __restrict__ Cout, int mode,
                                        float alpha) {
  __shared__ short As[128 * 64];
  __shared__ short Bs[128 * 64];
  const int t = threadIdx.x;
  const int wave = t >> 6, lane = t & 63;
  const int m = lane & 15, quad = lane >> 4;
  const int m0 = blockIdx.y * 128, n0 = blockIdx.x * 128;
  const int mh = (wave >> 1) * 64, nh = (wave & 1) * 64;
  const int r8 = lane >> 3;        // 0..7: row within wave's staging band
  const int c8 = (lane & 7) ^ r8;  // swizzled global chunk for this lane
  const int mx7 = m & 7;           // fragment-read swizzle key
  f32x4 acc[4][4];
#pragma unroll
  for (int i = 0; i < 4; ++i)
#pragma unroll
    for (int j = 0; j < 4; ++j) acc[i][j] = (f32x4){0.f, 0.f, 0.f, 0.f};

  for (int k0 = 0; k0 < ND; k0 += 64) {
    __syncthreads();  // prior iteration's fragment readers done
#pragma unroll
    for (int i = 0; i < 4; ++i) {
      int row = i * 32 + wave * 8 + r8;
      dma16(A + (size_t)(m0 + row) * ND + k0 + c8 * 8,
            As + (i * 256 + wave * 64) * 8);
      dma16(Bt + (size_t)(n0 + row) * ND + k0 + c8 * 8,
            Bs + (i * 256 + wave * 64) * 8);
    }
    __syncthreads();  // drains vmcnt: all DMA visible
    bf16x8 af[4][2], bf[4][2];
#pragma unroll
    for (int mt = 0; mt < 4; ++mt)
#pragma unroll
      for (int kc = 0; kc < 2; ++kc)
        af[mt][kc] = *(const bf16x8*)(As + (mh + mt * 16 + m) * 64 +
                                      ((kc * 4 + quad) ^ mx7) * 8);
#pragma unroll
    for (int nt = 0; nt < 4; ++nt)
#pragma unroll
      for (int kc = 0; kc < 2; ++kc)
        bf[nt][kc] = *(const bf16x8*)(Bs + (nh + nt * 16 + m) * 64 +
                                      ((kc * 4 + quad) ^ mx7) * 8);
#pragma unroll
    for (int mt = 0; mt < 4; ++mt)
#pragma unroll
      for (int nt = 0; nt < 4; ++nt)
#pragma unroll
        for (int kc = 0; kc < 2; ++kc)
          acc[mt][nt] = __builtin_amdgcn_mfma_f32_16x16x32_bf16(
              af[mt][kc], bf[nt][kc], acc[mt][nt], 0, 0, 0);
  }
  if (mode == 2) {
    // V^T scatter: value at (token row, channel col) -> Vt[b][h][d][s]
#pragma unroll
    for (int mt = 0; mt < 4; ++mt)
#pragma unroll
      for (int nt = 0; nt < 4; ++nt) {
        int row0 = m0 + mh + mt * 16 + quad * 4;
        int col = n0 + nh + nt * 16 + m;
        int b_ = row0 >> 11, s_ = row0 & (NS - 1);
        int h_ = col >> 6, d_ = col & (DEP - 1);
        uint2 p;
        p.x = pk2(acc[mt][nt][0] * alpha, acc[mt][nt][1] * alpha);
        p.y = pk2(acc[mt][nt][2] * alpha, acc[mt][nt][3] * alpha);
        *(uint2*)(Cout + (size_t)((b_ * NH + h_) * DEP + d_) * NS + s_) = p;
      }
  } else {
#pragma unroll
    for (int mt = 0; mt < 4; ++mt)
#pragma unroll
      for (int nt = 0; nt < 4; ++nt)
#pragma unroll
        for (int r = 0; r < 4; ++r) {
          int row = m0 + mh + mt * 16 + quad * 4 + r;
          int col = n0 + nh + nt * 16 + m;
          Cout[(size_t)row * ND + col] = f2b(acc[mt][nt][r] * alpha);
        }
  }
}

__global__ __launch_bounds__(256) void qkv_gemm(
    const short* __restrict__ xb, const short* __restrict__ yb,
    const short* __restrict__ Wqt, const short* __restrict__ Wkt,
    const short* __restrict__ Wvt, short* __restrict__ Qb,
    short* __restrict__ Kb, short* __restrict__ Vtb) {
  if (blockIdx.z == 0)
    gemm128(xb, Wqt, Qb, 1, QSCALE);  // scale + log2e folded into Q
  else if (blockIdx.z == 1)
    gemm128(yb, Wkt, Kb, 1, 1.0f);
  else
    gemm128(yb, Wvt, Vtb, 2, 1.0f);
}

// ---------------------------------------------------------------------------
// Output GEMM: 128x64 tile, BK=64, double-buffered DMA, swizzled LDS,
// fp32 row-major out.  Grid 512 = 2 blocks/CU.
// ---------------------------------------------------------------------------
__global__ __launch_bounds__(256) void out_gemm(const short* __restrict__ A,
                                                const short* __restrict__ Bt,
                                                float* __restrict__ Cout) {
  __shared__ short As[2][128 * 64];
  __shared__ short Bs[2][64 * 64];
  const int t = threadIdx.x;
  const int wave = t >> 6, lane = t & 63;
  const int m = lane & 15, quad = lane >> 4;
  const int m0 = blockIdx.y * 128, n0 = blockIdx.x * 64;
  const int mh = (wave >> 1) * 64, nh = (wave & 1) * 32;
  const int r8 = lane >> 3;
  const int c8 = (lane & 7) ^ r8;
  const int mx7 = m & 7;
  f32x4 acc[4][2];
#pragma unroll
  for (int i = 0; i < 4; ++i)
#pragma unroll
    for (int j = 0; j < 2; ++j) acc[i][j] = (f32x4){0.f, 0.f, 0.f, 0.f};

#pragma unroll
  for (int i = 0; i < 4; ++i)
    dma16(A + (size_t)(m0 + i * 32 + wave * 8 + r8) * ND + c8 * 8,
          As[0] + (i * 256 + wave * 64) * 8);
#pragma unroll
  for (int i = 0; i < 2; ++i)
    dma16(Bt + (size_t)(n0 + i * 32 + wave * 8 + r8) * ND + c8 * 8,
          Bs[0] + (i * 256 + wave * 64) * 8);

  int buf = 0;
  for (int k0 = 0; k0 < ND; k0 += 64, buf ^= 1) {
    __syncthreads();
    if (k0 + 64 < ND) {
#pragma unroll
      for (int i = 0; i < 4; ++i)
        dma16(A + (size_t)(m0 + i * 32 + wave * 8 + r8) * ND + k0 + 64 + c8 * 8,
              As[buf ^ 1] + (i * 256 + wave * 64) * 8);
#pragma unroll
      for (int i = 0; i < 2; ++i)
        dma16(Bt + (size_t)(n0 + i * 32 + wave * 8 + r8) * ND + k0 + 64 +
                  c8 * 8,
              Bs[buf ^ 1] + (i * 256 + wave * 64) * 8);
    }
    bf16x8 af[4][2], bf[2][2];
#pragma unroll
    for (int mt = 0; mt < 4; ++mt)
#pragma unroll
      for (int kc = 0; kc < 2; ++kc)
        af[mt][kc] = *(const bf16x8*)(As[buf] + (mh + mt * 16 + m) * 64 +
                                      ((kc * 4 + quad) ^ mx7) * 8);
#pragma unroll
    for (int nt = 0; nt < 2; ++nt)
#pragma unroll
      for (int kc = 0; kc < 2; ++kc)
        bf[nt][kc] = *(const bf16x8*)(Bs[buf] + (nh + nt * 16 + m) * 64 +
                                      ((kc * 4 + quad) ^ mx7) * 8);
#pragma unroll
    for (int mt = 0; mt < 4; ++mt)
#pragma unroll
      for (int nt = 0; nt < 2; ++nt)
#pragma unroll
        for (int kc = 0; kc < 2; ++kc)
          acc[mt][nt] = __builtin_amdgcn_mfma_f32_16x16x32_bf16(
              af[mt][kc], bf[nt][kc], acc[mt][nt], 0, 0, 0);
  }
#pragma unroll
  for (int mt = 0; mt < 4; ++mt)
#pragma unroll
    for (int nt = 0; nt < 2; ++nt)
#pragma unroll
      for (int r = 0; r < 4; ++r) {
        int row = m0 + mh + mt * 16 + quad * 4 + r;
        int col = n0 + nh + nt * 16 + m;
        Cout[(size_t)row * ND + col] = acc[mt][nt][r];
      }
}

// ---------------------------------------------------------------------------
// Flash attention, S^T formulation, 32x32x16 MFMA, in-register softmax,
// IN-BLOCK kv-split x2 (8 waves: 0-3 kv[0,1024), 4-7 kv[1024,2048)),
// T15 2-TILE PIPELINE: iteration t runs QK(t) [MFMA] alongside
// softmax+PV(t-1) [VALU/trans+MFMA] from saved St registers -- breaks the
// barrier-lockstep phase alignment so MFMA and VALU overlap within a wave.
// Slot schedule (2-deep buffers): at iter t issue K(t+1)->Ks[(t+1)&1] and
// V(t)->Vts[t&1]; QK(t) reads Ks[t&1]; PV(t-1) reads Vts[(t-1)&1].
// No within-iteration slot collision; cross-iteration separated by the
// single per-iteration barrier.  T5 setprio around MFMA clusters.
// Max-free softmax partials combine exactly in LDS: O=(O0+O1)/(l0+l1).
// ---------------------------------------------------------------------------
__global__ __launch_bounds__(512, 4) void attn_mfma(
    const short* __restrict__ Qb, const short* __restrict__ Kb,
    const short* __restrict__ Vtb, short* __restrict__ Ob) {
  __shared__ short Ks[2][2][64 * 64];   // [zh][slot][kv][d] swizzled
  __shared__ short Vts[2][2][64 * 64];  // [zh][slot][d][kv] swizzled
  const int t = threadIdx.x;
  const int wave = t >> 6, lane = t & 63;
  const int zh = wave >> 2, wl = wave & 3;  // kv-half, q-subtile
  const int l31 = lane & 31, hi = lane >> 5;
  const int sw = lane & 7;  // fragment-read swizzle key (row&7 == lane&7)
  const int bh = blockIdx.y, b = bh >> 3, h = bh & 7;
  const int q0 = blockIdx.x * 128 + wl * 32;
  const int kvb = zh * KVHALF;
  const size_t rowb = (size_t)b * NS;
  const short* Vtbase = Vtb + (size_t)(bh * DEP) * NS;
  const int r8 = lane >> 3;
  const int c8 = (lane & 7) ^ r8;

  // Q fragments (B-operand): col=q=l31, k(d) = dc*16 + hi*8 + j
  bf16x8 qf[4];
#pragma unroll
  for (int dc = 0; dc < 4; ++dc)
    qf[dc] = *(const bf16x8*)(Qb + (rowb + q0 + l31) * ND + h * DEP + dc * 16 +
                              hi * 8);

  // loop-invariant zero C-operand: avoids 32 v_mov per iteration (St init)
  f32x16 kzero;
#pragma unroll
  for (int i = 0; i < 16; ++i) kzero[i] = 0.f;

  float l_ = 0.0f;
  f32x16 Ot[2];
#pragma unroll
  for (int dt = 0; dt < 2; ++dt)
#pragma unroll
    for (int i = 0; i < 16; ++i) Ot[dt][i] = 0.f;

  f32x16 StA[2], StB[2];

  auto KDMA = [&](int tt) {  // stage K(tt) -> Ks[zh][tt&1]
#pragma unroll
    for (int i = 0; i < 2; ++i) {
      int row = i * 32 + wl * 8 + r8;
      dma16(Kb + (rowb + kvb + tt * 64 + row) * ND + h * DEP + c8 * 8,
            &Ks[zh][tt & 1][(i * 256 + wl * 64) * 8]);
    }
  };
  auto VDMA = [&](int tt) {  // stage V(tt) -> Vts[zh][tt&1]
#pragma unroll
    for (int i = 0; i < 2; ++i) {
      int row = i * 32 + wl * 8 + r8;
      dma16(Vtbase + (size_t)row * NS + kvb + tt * 64 + c8 * 8,
            &Vts[zh][tt & 1][(i * 256 + wl * 64) * 8]);
    }
  };
  auto QK = [&](int tt, f32x16 (&Sc)[2]) {  // reads Ks[zh][tt&1]
    const short* kb = &Ks[zh][tt & 1][0];
    __builtin_amdgcn_s_setprio(1);
#pragma unroll
    for (int kt = 0; kt < 2; ++kt) {
      bf16x8 kf0 = *(const bf16x8*)(kb + (kt * 32 + l31) * 64 + (hi ^ sw) * 8);
      Sc[kt] = __builtin_amdgcn_mfma_f32_32x32x16_bf16(kf0, qf[0], kzero,
                                                       0, 0, 0);
#pragma unroll
      for (int dc = 1; dc < 4; ++dc) {
        bf16x8 kf = *(const bf16x8*)(kb + (kt * 32 + l31) * 64 +
                                     ((dc * 2 + hi) ^ sw) * 8);
        Sc[kt] = __builtin_amdgcn_mfma_f32_32x32x16_bf16(kf, qf[dc], Sc[kt],
                                                         0, 0, 0);
      }
    }
    __builtin_amdgcn_s_setprio(0);
  };
  auto SMPV = [&](int tt, const f32x16 (&Sp)[2]) {  // reads Vts[zh][tt&1]
    // softmax (max-free, exp2) + in-register P^T -> B-fragment assembly.
    // Sp reg r (tile kt): kv = kt*32 + (r&3) + 8*(r>>2) + 4*hi.
    // B-frag slice s needs: elem j = P[s*16 + hi*8 + j][q].
    bf16x8 pf[4];
    float rs = 0.f;
#pragma unroll
    for (int s = 0; s < 4; ++s) {
      const int kt = s >> 1, base = (s & 1) * 8;
      float E[8];
#pragma unroll
      for (int j = 0; j < 8; ++j) {
        E[j] = __builtin_amdgcn_exp2f(Sp[kt][base + j]);
      }
      rs += ((E[0] + E[1]) + (E[2] + E[3])) + ((E[4] + E[5]) + (E[6] + E[7]));
      unsigned A0 = pk2(E[0], E[1]), A1 = pk2(E[2], E[3]);
      unsigned A2 = pk2(E[4], E[5]), A3 = pk2(E[6], E[7]);
      // swap: out0 = [a.lo | b.lo], out1 = [a.hi | b.hi]
      auto r02 =
          __builtin_amdgcn_permlane32_swap((int)A0, (int)A2, false, false);
      auto r13 =
          __builtin_amdgcn_permlane32_swap((int)A1, (int)A3, false, false);
      union { bf16x8 v; int u[4]; } pu;
      pu.u[0] = r02[0]; pu.u[1] = r13[0]; pu.u[2] = r02[1]; pu.u[3] = r13[1];
      pf[s] = pu.v;
    }
    l_ += rs;
    // PV: Ot^T[dt] += V^T[d, kv-slice] * P^T[kv-slice, q]
    const short* vb = &Vts[zh][tt & 1][0];
    __builtin_amdgcn_s_setprio(1);
#pragma unroll
    for (int dt = 0; dt < 2; ++dt)
#pragma unroll
      for (int s = 0; s < 4; ++s) {
        bf16x8 vf = *(const bf16x8*)(vb + (dt * 32 + l31) * 64 +
                                     ((s * 2 + hi) ^ sw) * 8);
        Ot[dt] = __builtin_amdgcn_mfma_f32_32x32x16_bf16(vf, pf[s], Ot[dt],
                                                         0, 0, 0);
      }
    __builtin_amdgcn_s_setprio(0);
  };

  // prologue: stage K(0); V(0) goes at iteration 0.
  KDMA(0);
  {  // t = 0: no softmax/PV yet
    __syncthreads();
    KDMA(1);
    VDMA(0);
    QK(0, StA);
  }
  for (int j = 0; j < 7; ++j) {  // t = 2j+1 (odd->StB), t = 2j+2 (even->StA)
    const int t1 = 2 * j + 1, t2 = 2 * j + 2;
    __syncthreads();
    KDMA(t1 + 1);
    VDMA(t1);
    QK(t1, StB);
    SMPV(t1 - 1, StA);
    __syncthreads();
    KDMA(t2 + 1);
    VDMA(t2);
    QK(t2, StA);
    SMPV(t2 - 1, StB);
  }
  {  // t = 15: last QK (no K(16))
    __syncthreads();
    VDMA(15);
    QK(15, StB);
    SMPV(14, StA);
  }
  // epilogue: V(15) landed (all waves) after this barrier
  __syncthreads();
  SMPV(15, StB);

  // per-wave denominator partial: lane l and l^32 hold complementary kv sets
  l_ += __shfl_xor(l_, 32, 64);

  // cross-half combine in LDS (aliased over dead K/V staging buffers).
  __syncthreads();  // all K/V fragment reads of the last tile complete
  float* Ox = (float*)Ks;   // [4][64][32] fp32 = 32 KB
  float* lx = (float*)Vts;  // [4][32] fp32
  if (zh == 1) {
#pragma unroll
    for (int dt = 0; dt < 2; ++dt)
#pragma unroll
      for (int r = 0; r < 16; ++r) {
        int d = dt * 32 + (r & 3) + 8 * (r >> 2) + 4 * hi;
        Ox[(wl * 64 + d) * 32 + l31] = Ot[dt][r];
      }
    if (lane < 32) lx[wl * 32 + l31] = l_;
  }
  __syncthreads();
  if (zh == 0) {
    float linv = 1.0f / (l_ + lx[wl * 32 + l31]);
    size_t row = rowb + q0 + l31;
    // Ot reg r (tile dt): d = dt*32 + (r&3) + 8*(r>>2) + 4*hi -> 8B stores
#pragma unroll
    for (int dt = 0; dt < 2; ++dt)
#pragma unroll
      for (int g = 0; g < 4; ++g) {
        int d0 = dt * 32 + g * 8 + hi * 4;
        float o[4];
#pragma unroll
        for (int j = 0; j < 4; ++j)
          o[j] = Ot[dt][g * 4 + j] + Ox[(wl * 64 + d0 + j) * 32 + l31];
        uint2 pk;
        pk.x = pk2(o[0] * linv, o[1] * linv);
        pk.y = pk2(o[2] * linv, o[3] * linv);
        *(uint2*)(Ob + row * ND + h * DEP + d0) = pk;
      }
  }
}

// ---------------------------------------------------------------------------
extern "C" void kernel_launch(void* const* d_in, const int* in_sizes, int n_in,
                              void* d_out, int out_size, void* d_ws,
                              size_t ws_size, hipStream_t stream) {
  const float* x = (const float*)d_in[0];
  const float* y = (const float*)d_in[1];
  const float* Wq = (const float*)d_in[2];
  const float* Wk = (const float*)d_in[3];
  const float* Wv = (const float*)d_in[4];
  const float* Wo = (const float*)d_in[5];
  float* out = (float*)d_out;

  const size_t mat = (size_t)NB * NS * ND;
  const size_t wsz = (size_t)ND * ND;
  short* xb = (short*)d_ws;
  short* yb = xb + mat;
  short* Wqt = yb + mat;
  short* Wkt = Wqt + wsz;
  short* Wvt = Wkt + wsz;
  short* Wot = Wvt + wsz;
  short* Qb = Wot + wsz;
  short* Kb = Qb + mat;
  short* Vtb = Kb + mat;
  short* attnb = xb;  // reuse: xb dead after QKV GEMM

  prep<<<dim3(mat / 1024, 3), 256, 0, stream>>>(x, y, Wq, Wk, Wv, Wo, xb, yb,
                                                Wqt, Wkt, Wvt, Wot);
  qkv_gemm<<<dim3(ND / 128, (NB * NS) / 128, 3), 256, 0, stream>>>(
      xb, yb, Wqt, Wkt, Wvt, Qb, Kb, Vtb);
  attn_mfma<<<dim3(NS / 128, NB * NH), 512, 0, stream>>>(Qb, Kb, Vtb, attnb);
  out_gemm<<<dim3(ND / 64, (NB * NS) / 128), 256, 0, stream>>>(attnb, Wot,
                                                               out);
}

// Round 5
// 206.964 us; speedup vs baseline: 1.0762x; 1.0762x over previous
//
#include <hip/hip_runtime.h>
#include <hip/hip_bf16.h>
#include <math.h>
#include <stdint.h>

#define NB 4
#define NS 2048
#define ND 512
#define NH 8
#define DEP 64
#define KVHALF (NS / 2)

typedef __attribute__((ext_vector_type(8))) short bf16x8;
typedef __attribute__((ext_vector_type(4))) short bf16x4;
typedef __attribute__((ext_vector_type(4))) float f32x4;
typedef __attribute__((ext_vector_type(16))) float f32x16;

#define QSCALE 0.18033688011112042f  // DEPTH^-0.5 * log2(e): softmax in exp2

__device__ __forceinline__ short f2b(float f) {
  unsigned u = __float_as_uint(f);
  u += 0x7FFF + ((u >> 16) & 1);  // RNE
  return (short)(u >> 16);
}
__device__ __forceinline__ unsigned pk2(float a, float b) {
  union { __hip_bfloat162 h; unsigned u; } c;
  c.h = __float22bfloat162_rn(float2{a, b});
  return c.u;
}
// async 16B global->LDS DMA; LDS dest is wave-uniform base + lane*16
__device__ __forceinline__ void dma16(const void* g, void* l) {
  __builtin_amdgcn_global_load_lds(
      (const __attribute__((address_space(1))) void*)g,
      (__attribute__((address_space(3))) void*)l, 16, 0, 0);
}

// ---------------------------------------------------------------------------
// prep: one launch does BOTH input casts and all 4 weight transposes.
// grid (4096, 3): y=0 cast x, y=1 cast y, y=2 (x<256) transpose W0..W3.
// ---------------------------------------------------------------------------
__global__ __launch_bounds__(256) void prep(
    const float* __restrict__ x, const float* __restrict__ y,
    const float* __restrict__ W0, const float* __restrict__ W1,
    const float* __restrict__ W2, const float* __restrict__ W3,
    short* __restrict__ xb, short* __restrict__ yb, short* __restrict__ T0,
    short* __restrict__ T1, short* __restrict__ T2, short* __restrict__ T3) {
  const int t = threadIdx.x;
  if (blockIdx.y < 2) {
    const float* src = blockIdx.y ? y : x;
    short* dst = blockIdx.y ? yb : xb;
    size_t i = ((size_t)blockIdx.x * 256 + t) * 4;
    float4 v = *(const float4*)(src + i);
    bf16x4 o;
    o[0] = f2b(v.x); o[1] = f2b(v.y); o[2] = f2b(v.z); o[3] = f2b(v.w);
    *(bf16x4*)(dst + i) = o;
    return;
  }
  const int bx = blockIdx.x;
  if (bx >= 256) return;
  const int wj = bx >> 6, rem = bx & 63;
  const float* W = wj == 0 ? W0 : wj == 1 ? W1 : wj == 2 ? W2 : W3;
  short* T = wj == 0 ? T0 : wj == 1 ? T1 : wj == 2 ? T2 : T3;
  __shared__ float tile[64][65];
  const int k0 = (rem >> 3) * 64, n0 = (rem & 7) * 64;
#pragma unroll
  for (int i = 0; i < 4; ++i) {
    int r = (t >> 4) + i * 16;
    int c = (t & 15) * 4;
    float4 v = *(const float4*)&W[(size_t)(k0 + r) * ND + n0 + c];
    tile[r][c] = v.x; tile[r][c + 1] = v.y;
    tile[r][c + 2] = v.z; tile[r][c + 3] = v.w;
  }
  __syncthreads();
#pragma unroll
  for (int i = 0; i < 4; ++i) {
    int n = (t >> 4) + i * 16;
    int kc = (t & 15) * 4;
    bf16x4 o;
#pragma unroll
    for (int j = 0; j < 4; ++j) o[j] = f2b(tile[kc + j][n]);
    *(bf16x4*)&T[(size_t)(n0 + n) * ND + k0 + kc] = o;
  }
}

// ---------------------------------------------------------------------------
// QKV GEMM: 128x128 tile, 4 waves each 64x64 (acc 4x4), BK=64, single-buffer
// DMA staging (m97 2-barrier), XOR-swizzled LDS (pitch 64, chunk ^= row&7).
// mode 1: bf16 row-major out; 2: bf16 V^T out.
// ---------------------------------------------------------------------------
__device__ __forceinline__ void gemm128(const short* __restrict__ A,
                                        const short* __restrict__ Bt,
                                        short* __restrict__ Cout, int mode,
                                        float alpha) {
  __shared__ short As[128 * 64];
  __shared__ short Bs[128 * 64];
  const int t = threadIdx.x;
  const int wave = t >> 6, lane = t & 63;
  const int m = lane & 15, quad = lane >> 4;
  const int m0 = blockIdx.y * 128, n0 = blockIdx.x * 128;
  const int mh = (wave >> 1) * 64, nh = (wave & 1) * 64;
  const int r8 = lane >> 3;        // 0..7: row within wave's staging band
  const int c8 = (lane & 7) ^ r8;  // swizzled global chunk for this lane
  const int mx7 = m & 7;           // fragment-read swizzle key
  f32x4 acc[4][4];
#pragma unroll
  for (int i = 0; i < 4; ++i)
#pragma unroll
    for (int j = 0; j < 4; ++j) acc[i][j] = (f32x4){0.f, 0.f, 0.f, 0.f};

  for (int k0 = 0; k0 < ND; k0 += 64) {
    __syncthreads();  // prior iteration's fragment readers done
#pragma unroll
    for (int i = 0; i < 4; ++i) {
      int row = i * 32 + wave * 8 + r8;
      dma16(A + (size_t)(m0 + row) * ND + k0 + c8 * 8,
            As + (i * 256 + wave * 64) * 8);
      dma16(Bt + (size_t)(n0 + row) * ND + k0 + c8 * 8,
            Bs + (i * 256 + wave * 64) * 8);
    }
    __syncthreads();  // drains vmcnt: all DMA visible
    bf16x8 af[4][2], bf[4][2];
#pragma unroll
    for (int mt = 0; mt < 4; ++mt)
#pragma unroll
      for (int kc = 0; kc < 2; ++kc)
        af[mt][kc] = *(const bf16x8*)(As + (mh + mt * 16 + m) * 64 +
                                      ((kc * 4 + quad) ^ mx7) * 8);
#pragma unroll
    for (int nt = 0; nt < 4; ++nt)
#pragma unroll
      for (int kc = 0; kc < 2; ++kc)
        bf[nt][kc] = *(const bf16x8*)(Bs + (nh + nt * 16 + m) * 64 +
                                      ((kc * 4 + quad) ^ mx7) * 8);
#pragma unroll
    for (int mt = 0; mt < 4; ++mt)
#pragma unroll
      for (int nt = 0; nt < 4; ++nt)
#pragma unroll
        for (int kc = 0; kc < 2; ++kc)
          acc[mt][nt] = __builtin_amdgcn_mfma_f32_16x16x32_bf16(
              af[mt][kc], bf[nt][kc], acc[mt][nt], 0, 0, 0);
  }
  if (mode == 2) {
    // V^T scatter: value at (token row, channel col) -> Vt[b][h][d][s]
#pragma unroll
    for (int mt = 0; mt < 4; ++mt)
#pragma unroll
      for (int nt = 0; nt < 4; ++nt) {
        int row0 = m0 + mh + mt * 16 + quad * 4;
        int col = n0 + nh + nt * 16 + m;
        int b_ = row0 >> 11, s_ = row0 & (NS - 1);
        int h_ = col >> 6, d_ = col & (DEP - 1);
        uint2 p;
        p.x = pk2(acc[mt][nt][0] * alpha, acc[mt][nt][1] * alpha);
        p.y = pk2(acc[mt][nt][2] * alpha, acc[mt][nt][3] * alpha);
        *(uint2*)(Cout + (size_t)((b_ * NH + h_) * DEP + d_) * NS + s_) = p;
      }
  } else {
#pragma unroll
    for (int mt = 0; mt < 4; ++mt)
#pragma unroll
      for (int nt = 0; nt < 4; ++nt)
#pragma unroll
        for (int r = 0; r < 4; ++r) {
          int row = m0 + mh + mt * 16 + quad * 4 + r;
          int col = n0 + nh + nt * 16 + m;
          Cout[(size_t)row * ND + col] = f2b(acc[mt][nt][r] * alpha);
        }
  }
}

__global__ __launch_bounds__(256) void qkv_gemm(
    const short* __restrict__ xb, const short* __restrict__ yb,
    const short* __restrict__ Wqt, const short* __restrict__ Wkt,
    const short* __restrict__ Wvt, short* __restrict__ Qb,
    short* __restrict__ Kb, short* __restrict__ Vtb) {
  if (blockIdx.z == 0)
    gemm128(xb, Wqt, Qb, 1, QSCALE);  // scale + log2e folded into Q
  else if (blockIdx.z == 1)
    gemm128(yb, Wkt, Kb, 1, 1.0f);
  else
    gemm128(yb, Wvt, Vtb, 2, 1.0f);
}

// ---------------------------------------------------------------------------
// Output GEMM: 128x64 tile, BK=64, double-buffered DMA, swizzled LDS,
// fp32 row-major out.  Grid 512 = 2 blocks/CU.
// ---------------------------------------------------------------------------
__global__ __launch_bounds__(256) void out_gemm(const short* __restrict__ A,
                                                const short* __restrict__ Bt,
                                                float* __restrict__ Cout) {
  __shared__ short As[2][128 * 64];
  __shared__ short Bs[2][64 * 64];
  const int t = threadIdx.x;
  const int wave = t >> 6, lane = t & 63;
  const int m = lane & 15, quad = lane >> 4;
  const int m0 = blockIdx.y * 128, n0 = blockIdx.x * 64;
  const int mh = (wave >> 1) * 64, nh = (wave & 1) * 32;
  const int r8 = lane >> 3;
  const int c8 = (lane & 7) ^ r8;
  const int mx7 = m & 7;
  f32x4 acc[4][2];
#pragma unroll
  for (int i = 0; i < 4; ++i)
#pragma unroll
    for (int j = 0; j < 2; ++j) acc[i][j] = (f32x4){0.f, 0.f, 0.f, 0.f};

#pragma unroll
  for (int i = 0; i < 4; ++i)
    dma16(A + (size_t)(m0 + i * 32 + wave * 8 + r8) * ND + c8 * 8,
          As[0] + (i * 256 + wave * 64) * 8);
#pragma unroll
  for (int i = 0; i < 2; ++i)
    dma16(Bt + (size_t)(n0 + i * 32 + wave * 8 + r8) * ND + c8 * 8,
          Bs[0] + (i * 256 + wave * 64) * 8);

  int buf = 0;
  for (int k0 = 0; k0 < ND; k0 += 64, buf ^= 1) {
    __syncthreads();
    if (k0 + 64 < ND) {
#pragma unroll
      for (int i = 0; i < 4; ++i)
        dma16(A + (size_t)(m0 + i * 32 + wave * 8 + r8) * ND + k0 + 64 + c8 * 8,
              As[buf ^ 1] + (i * 256 + wave * 64) * 8);
#pragma unroll
      for (int i = 0; i < 2; ++i)
        dma16(Bt + (size_t)(n0 + i * 32 + wave * 8 + r8) * ND + k0 + 64 +
                  c8 * 8,
              Bs[buf ^ 1] + (i * 256 + wave * 64) * 8);
    }
    bf16x8 af[4][2], bf[2][2];
#pragma unroll
    for (int mt = 0; mt < 4; ++mt)
#pragma unroll
      for (int kc = 0; kc < 2; ++kc)
        af[mt][kc] = *(const bf16x8*)(As[buf] + (mh + mt * 16 + m) * 64 +
                                      ((kc * 4 + quad) ^ mx7) * 8);
#pragma unroll
    for (int nt = 0; nt < 2; ++nt)
#pragma unroll
      for (int kc = 0; kc < 2; ++kc)
        bf[nt][kc] = *(const bf16x8*)(Bs[buf] + (nh + nt * 16 + m) * 64 +
                                      ((kc * 4 + quad) ^ mx7) * 8);
#pragma unroll
    for (int mt = 0; mt < 4; ++mt)
#pragma unroll
      for (int nt = 0; nt < 2; ++nt)
#pragma unroll
        for (int kc = 0; kc < 2; ++kc)
          acc[mt][nt] = __builtin_amdgcn_mfma_f32_16x16x32_bf16(
              af[mt][kc], bf[nt][kc], acc[mt][nt], 0, 0, 0);
  }
#pragma unroll
  for (int mt = 0; mt < 4; ++mt)
#pragma unroll
    for (int nt = 0; nt < 2; ++nt)
#pragma unroll
      for (int r = 0; r < 4; ++r) {
        int row = m0 + mh + mt * 16 + quad * 4 + r;
        int col = n0 + nh + nt * 16 + m;
        Cout[(size_t)row * ND + col] = acc[mt][nt][r];
      }
}

// ---------------------------------------------------------------------------
// Flash attention, S^T formulation, 32x32x16 MFMA, in-register softmax,
// IN-BLOCK kv-split x2 (8 waves: 0-3 kv[0,1024), 4-7 kv[1024,2048)).
// pf-PIPELINE (register-frugal T15): iteration t computes QK(t)+softmax(t)
// and PV(t-1) from the PREVIOUS tile's packed pf registers -- PV's
// independent MFMA stream fills the QK->softmax dependency gap and overlaps
// the exp2/pack VALU burst.  Only pf[4] (16 VGPRs) is carried across the
// barrier (r4 carried St[2]x2 = 64 VGPRs via lambda array-refs -> scratch
// spill, 155 MB WRITE_SIZE).  All macros, named St0/St1, literal indices.
// Slot schedule: at iter t issue K(t+1)->Ks[(t+1)&1], V(t)->Vts[t&1];
// QK(t) reads Ks[t&1]; PV(t-1) reads Vts[(t-1)&1].  No collisions.
// Max-free softmax partials combine exactly in LDS: O=(O0+O1)/(l0+l1).
// ---------------------------------------------------------------------------
__global__ __launch_bounds__(512, 4) void attn_mfma(
    const short* __restrict__ Qb, const short* __restrict__ Kb,
    const short* __restrict__ Vtb, short* __restrict__ Ob) {
  __shared__ short Ks[2][2][64 * 64];   // [zh][slot][kv][d] swizzled
  __shared__ short Vts[2][2][64 * 64];  // [zh][slot][d][kv] swizzled
  const int t = threadIdx.x;
  const int wave = t >> 6, lane = t & 63;
  const int zh = wave >> 2, wl = wave & 3;  // kv-half, q-subtile
  const int l31 = lane & 31, hi = lane >> 5;
  const int sw = lane & 7;  // fragment-read swizzle key (row&7 == lane&7)
  const int bh = blockIdx.y, b = bh >> 3, h = bh & 7;
  const int q0 = blockIdx.x * 128 + wl * 32;
  const int kvb = zh * KVHALF;
  const size_t rowb = (size_t)b * NS;
  const short* Vtbase = Vtb + (size_t)(bh * DEP) * NS;
  const int r8 = lane >> 3;
  const int c8 = (lane & 7) ^ r8;

  // Q fragments (B-operand): col=q=l31, k(d) = dc*16 + hi*8 + j
  bf16x8 qf[4];
#pragma unroll
  for (int dc = 0; dc < 4; ++dc)
    qf[dc] = *(const bf16x8*)(Qb + (rowb + q0 + l31) * ND + h * DEP + dc * 16 +
                              hi * 8);

  // loop-invariant zero C-operand (St init without per-iter v_movs)
  f32x16 kzero;
#pragma unroll
  for (int i = 0; i < 16; ++i) kzero[i] = 0.f;

  float l_ = 0.0f;
  f32x16 Ot[2];
#pragma unroll
  for (int dt = 0; dt < 2; ++dt)
#pragma unroll
    for (int i = 0; i < 16; ++i) Ot[dt][i] = 0.f;

  f32x16 St0, St1;        // current tile S^T (dies within the iteration)
  bf16x8 pfA[4], pfB[4];  // packed P^T fragments, pipelined across barrier

#define KDMA(tt)                                                          \
  {                                                                       \
    _Pragma("unroll") for (int i_ = 0; i_ < 2; ++i_) {                    \
      int row_ = i_ * 32 + wl * 8 + r8;                                   \
      dma16(Kb + (rowb + kvb + (tt) * 64 + row_) * ND + h * DEP + c8 * 8, \
            &Ks[zh][(tt) & 1][(i_ * 256 + wl * 64) * 8]);                 \
    }                                                                     \
  }
#define VDMA(tt)                                                       \
  {                                                                    \
    _Pragma("unroll") for (int i_ = 0; i_ < 2; ++i_) {                 \
      int row_ = i_ * 32 + wl * 8 + r8;                                \
      dma16(Vtbase + (size_t)row_ * NS + kvb + (tt) * 64 + c8 * 8,     \
            &Vts[zh][(tt) & 1][(i_ * 256 + wl * 64) * 8]);             \
    }                                                                  \
  }
// QK(tt): St0/St1 = K-tile x Q (S^T: kv = kt*32+row, q = col = l31)
#define QKH(SD, KT, kb_)                                                     \
  {                                                                          \
    bf16x8 kf_;                                                              \
    kf_ = *(const bf16x8*)((kb_) + ((KT)*32 + l31) * 64 + ((0 + hi) ^ sw) * 8); \
    SD = __builtin_amdgcn_mfma_f32_32x32x16_bf16(kf_, qf[0], kzero, 0, 0, 0); \
    kf_ = *(const bf16x8*)((kb_) + ((KT)*32 + l31) * 64 + ((2 + hi) ^ sw) * 8); \
    SD = __builtin_amdgcn_mfma_f32_32x32x16_bf16(kf_, qf[1], SD, 0, 0, 0);   \
    kf_ = *(const bf16x8*)((kb_) + ((KT)*32 + l31) * 64 + ((4 + hi) ^ sw) * 8); \
    SD = __builtin_amdgcn_mfma_f32_32x32x16_bf16(kf_, qf[2], SD, 0, 0, 0);   \
    kf_ = *(const bf16x8*)((kb_) + ((KT)*32 + l31) * 64 + ((6 + hi) ^ sw) * 8); \
    SD = __builtin_amdgcn_mfma_f32_32x32x16_bf16(kf_, qf[3], SD, 0, 0, 0);   \
  }
#define QK(tt)                                  \
  {                                             \
    const short* kb_ = &Ks[zh][(tt) & 1][0];    \
    __builtin_amdgcn_s_setprio(1);              \
    QKH(St0, 0, kb_);                           \
    QKH(St1, 1, kb_);                           \
    __builtin_amdgcn_s_setprio(0);              \
  }
// softmax slice: exp2 on 8 St values, pack to bf16, permlane-redistribute.
// St reg r: kv = kt*32 + (r&3) + 8*(r>>2) + 4*hi; B-frag slice s elem j =
// P[s*16 + hi*8 + j][q].
#define SM_SLICE(SS, BASE, SIDX, PF)                                         \
  {                                                                          \
    float E0 = __builtin_amdgcn_exp2f(SS[(BASE) + 0]);                       \
    float E1 = __builtin_amdgcn_exp2f(SS[(BASE) + 1]);                       \
    float E2 = __builtin_amdgcn_exp2f(SS[(BASE) + 2]);                       \
    float E3 = __builtin_amdgcn_exp2f(SS[(BASE) + 3]);                       \
    float E4 = __builtin_amdgcn_exp2f(SS[(BASE) + 4]);                       \
    float E5 = __builtin_amdgcn_exp2f(SS[(BASE) + 5]);                       \
    float E6 = __builtin_amdgcn_exp2f(SS[(BASE) + 6]);                       \
    float E7 = __builtin_amdgcn_exp2f(SS[(BASE) + 7]);                       \
    l_ += ((E0 + E1) + (E2 + E3)) + ((E4 + E5) + (E6 + E7));                 \
    unsigned A0 = pk2(E0, E1), A1 = pk2(E2, E3);                             \
    unsigned A2 = pk2(E4, E5), A3 = pk2(E6, E7);                             \
    auto r02 =                                                               \
        __builtin_amdgcn_permlane32_swap((int)A0, (int)A2, false, false);    \
    auto r13 =                                                               \
        __builtin_amdgcn_permlane32_swap((int)A1, (int)A3, false, false);    \
    union { bf16x8 v; int u[4]; } pu_;                                       \
    pu_.u[0] = r02[0]; pu_.u[1] = r13[0]; pu_.u[2] = r02[1];                 \
    pu_.u[3] = r13[1];                                                       \
    PF[SIDX] = pu_.v;                                                        \
  }
#define SM(PF)                  \
  SM_SLICE(St0, 0, 0, PF)       \
  SM_SLICE(St0, 8, 1, PF)       \
  SM_SLICE(St1, 0, 2, PF)       \
  SM_SLICE(St1, 8, 3, PF)
// PV(tt, PF): Ot^T[dt] += V^T[d, kv-slice] * P^T[kv-slice, q]
#define PV(tt, PF)                                                         \
  {                                                                        \
    const short* vb_ = &Vts[zh][(tt) & 1][0];                              \
    __builtin_amdgcn_s_setprio(1);                                         \
    _Pragma("unroll") for (int dt_ = 0; dt_ < 2; ++dt_) {                  \
      _Pragma("unroll") for (int s_ = 0; s_ < 4; ++s_) {                   \
        bf16x8 vf_ = *(const bf16x8*)(vb_ + (dt_ * 32 + l31) * 64 +        \
                                      ((s_ * 2 + hi) ^ sw) * 8);           \
        Ot[dt_] = __builtin_amdgcn_mfma_f32_32x32x16_bf16(vf_, PF[s_],     \
                                                          Ot[dt_], 0, 0, 0); \
      }                                                                    \
    }                                                                      \
    __builtin_amdgcn_s_setprio(0);                                         \
  }

  // prologue
  KDMA(0);
  __syncthreads();  // K(0) landed
  KDMA(1);
  VDMA(0);
  QK(0);
  SM(pfA);  // t=0: no PV yet
#pragma unroll 1
  for (int j = 0; j < 7; ++j) {  // t = 2j+1 and 2j+2 (covers t=1..14)
    const int t1 = 2 * j + 1, t2 = 2 * j + 2;
    __syncthreads();  // K(t1), V(t1-1) landed; slot readers done
    KDMA(t1 + 1);
    VDMA(t1);
    QK(t1);          // Ks slot 1
    PV(t1 - 1, pfA); // Vts slot 0; independent MFMA under QK->SM gap
    SM(pfB);
    __syncthreads();
    KDMA(t2 + 1);
    VDMA(t2);
    QK(t2);          // Ks slot 0
    PV(t2 - 1, pfB); // Vts slot 1
    SM(pfA);
  }
  {  // t = 15: last QK (no K(16))
    __syncthreads();
    VDMA(15);
    QK(15);
    PV(14, pfA);
    SM(pfB);
  }
  __syncthreads();  // V(15) landed
  PV(15, pfB);

  // per-wave denominator partial: lane l and l^32 hold complementary kv sets
  l_ += __shfl_xor(l_, 32, 64);

  // cross-half combine in LDS (aliased over dead K/V staging buffers).
  __syncthreads();  // all K/V fragment reads of the last tile complete
  float* Ox = (float*)Ks;   // [4][64][32] fp32 = 32 KB
  float* lx = (float*)Vts;  // [4][32] fp32
  if (zh == 1) {
#pragma unroll
    for (int dt = 0; dt < 2; ++dt)
#pragma unroll
      for (int r = 0; r < 16; ++r) {
        int d = dt * 32 + (r & 3) + 8 * (r >> 2) + 4 * hi;
        Ox[(wl * 64 + d) * 32 + l31] = Ot[dt][r];
      }
    if (lane < 32) lx[wl * 32 + l31] = l_;
  }
  __syncthreads();
  if (zh == 0) {
    float linv = 1.0f / (l_ + lx[wl * 32 + l31]);
    size_t row = rowb + q0 + l31;
    // Ot reg r (tile dt): d = dt*32 + (r&3) + 8*(r>>2) + 4*hi -> 8B stores
#pragma unroll
    for (int dt = 0; dt < 2; ++dt)
#pragma unroll
      for (int g = 0; g < 4; ++g) {
        int d0 = dt * 32 + g * 8 + hi * 4;
        float o[4];
#pragma unroll
        for (int jj = 0; jj < 4; ++jj)
          o[jj] = Ot[dt][g * 4 + jj] + Ox[(wl * 64 + d0 + jj) * 32 + l31];
        uint2 pk;
        pk.x = pk2(o[0] * linv, o[1] * linv);
        pk.y = pk2(o[2] * linv, o[3] * linv);
        *(uint2*)(Ob + row * ND + h * DEP + d0) = pk;
      }
  }
#undef KDMA
#undef VDMA
#undef QKH
#undef QK
#undef SM_SLICE
#undef SM
#undef PV
}

// ---------------------------------------------------------------------------
extern "C" void kernel_launch(void* const* d_in, const int* in_sizes, int n_in,
                              void* d_out, int out_size, void* d_ws,
                              size_t ws_size, hipStream_t stream) {
  const float* x = (const float*)d_in[0];
  const float* y = (const float*)d_in[1];
  const float* Wq = (const float*)d_in[2];
  const float* Wk = (const float*)d_in[3];
  const float* Wv = (const float*)d_in[4];
  const float* Wo = (const float*)d_in[5];
  float* out = (float*)d_out;

  const size_t mat = (size_t)NB * NS * ND;
  const size_t wsz = (size_t)ND * ND;
  short* xb = (short*)d_ws;
  short* yb = xb + mat;
  short* Wqt = yb + mat;
  short* Wkt = Wqt + wsz;
  short* Wvt = Wkt + wsz;
  short* Wot = Wvt + wsz;
  short* Qb = Wot + wsz;
  short* Kb = Qb + mat;
  short* Vtb = Kb + mat;
  short* attnb = xb;  // reuse: xb dead after QKV GEMM

  prep<<<dim3(mat / 1024, 3), 256, 0, stream>>>(x, y, Wq, Wk, Wv, Wo, xb, yb,
                                                Wqt, Wkt, Wvt, Wot);
  qkv_gemm<<<dim3(ND / 128, (NB * NS) / 128, 3), 256, 0, stream>>>(
      xb, yb, Wqt, Wkt, Wvt, Qb, Kb, Vtb);
  attn_mfma<<<dim3(NS / 128, NB * NH), 512, 0, stream>>>(Qb, Kb, Vtb, attnb);
  out_gemm<<<dim3(ND / 64, (NB * NS) / 128), 256, 0, stream>>>(attnb, Wot,
                                                               out);
}

// Round 6
// 198.953 us; speedup vs baseline: 1.1196x; 1.0403x over previous
//
#include <hip/hip_runtime.h>
#include <hip/hip_bf16.h>
#include <math.h>
#include <stdint.h>

#define NB 4
#define NS 2048
#define ND 512
#define NH 8
#define DEP 64
#define KVHALF (NS / 2)

typedef __attribute__((ext_vector_type(8))) short bf16x8;
typedef __attribute__((ext_vector_type(4))) short bf16x4;
typedef __attribute__((ext_vector_type(4))) float f32x4;
typedef __attribute__((ext_vector_type(16))) float f32x16;

#define QSCALE 0.18033688011112042f  // DEPTH^-0.5 * log2(e): softmax in exp2

__device__ __forceinline__ short f2b(float f) {
  unsigned u = __float_as_uint(f);
  u += 0x7FFF + ((u >> 16) & 1);  // RNE
  return (short)(u >> 16);
}
__device__ __forceinline__ unsigned pk2(float a, float b) {
  union { __hip_bfloat162 h; unsigned u; } c;
  c.h = __float22bfloat162_rn(float2{a, b});
  return c.u;
}
// async 16B global->LDS DMA; LDS dest is wave-uniform base + lane*16
__device__ __forceinline__ void dma16(const void* g, void* l) {
  __builtin_amdgcn_global_load_lds(
      (const __attribute__((address_space(1))) void*)g,
      (__attribute__((address_space(3))) void*)l, 16, 0, 0);
}

// ---------------------------------------------------------------------------
// prep: one launch does BOTH input casts and all 4 weight transposes.
// grid (4096, 3): y=0 cast x, y=1 cast y, y=2 (x<256) transpose W0..W3.
// ---------------------------------------------------------------------------
__global__ __launch_bounds__(256) void prep(
    const float* __restrict__ x, const float* __restrict__ y,
    const float* __restrict__ W0, const float* __restrict__ W1,
    const float* __restrict__ W2, const float* __restrict__ W3,
    short* __restrict__ xb, short* __restrict__ yb, short* __restrict__ T0,
    short* __restrict__ T1, short* __restrict__ T2, short* __restrict__ T3) {
  const int t = threadIdx.x;
  if (blockIdx.y < 2) {
    const float* src = blockIdx.y ? y : x;
    short* dst = blockIdx.y ? yb : xb;
    size_t i = ((size_t)blockIdx.x * 256 + t) * 4;
    float4 v = *(const float4*)(src + i);
    bf16x4 o;
    o[0] = f2b(v.x); o[1] = f2b(v.y); o[2] = f2b(v.z); o[3] = f2b(v.w);
    *(bf16x4*)(dst + i) = o;
    return;
  }
  const int bx = blockIdx.x;
  if (bx >= 256) return;
  const int wj = bx >> 6, rem = bx & 63;
  const float* W = wj == 0 ? W0 : wj == 1 ? W1 : wj == 2 ? W2 : W3;
  short* T = wj == 0 ? T0 : wj == 1 ? T1 : wj == 2 ? T2 : T3;
  __shared__ float tile[64][65];
  const int k0 = (rem >> 3) * 64, n0 = (rem & 7) * 64;
#pragma unroll
  for (int i = 0; i < 4; ++i) {
    int r = (t >> 4) + i * 16;
    int c = (t & 15) * 4;
    float4 v = *(const float4*)&W[(size_t)(k0 + r) * ND + n0 + c];
    tile[r][c] = v.x; tile[r][c + 1] = v.y;
    tile[r][c + 2] = v.z; tile[r][c + 3] = v.w;
  }
  __syncthreads();
#pragma unroll
  for (int i = 0; i < 4; ++i) {
    int n = (t >> 4) + i * 16;
    int kc = (t & 15) * 4;
    bf16x4 o;
#pragma unroll
    for (int j = 0; j < 4; ++j) o[j] = f2b(tile[kc + j][n]);
    *(bf16x4*)&T[(size_t)(n0 + n) * ND + k0 + kc] = o;
  }
}

// ---------------------------------------------------------------------------
// QKV GEMM: 128x128 tile, 4 waves each 64x64 (acc 4x4), BK=64, single-buffer
// DMA staging (m97 2-barrier), XOR-swizzled LDS (pitch 64, chunk ^= row&7).
// mode 1: bf16 row-major out; 2: bf16 V^T out.
// ---------------------------------------------------------------------------
__device__ __forceinline__ void gemm128(const short* __restrict__ A,
                                        const short* __restrict__ Bt,
                                        short* __restrict__ Cout, int mode,
                                        float alpha) {
  __shared__ short As[128 * 64];
  __shared__ short Bs[128 * 64];
  const int t = threadIdx.x;
  const int wave = t >> 6, lane = t & 63;
  const int m = lane & 15, quad = lane >> 4;
  const int m0 = blockIdx.y * 128, n0 = blockIdx.x * 128;
  const int mh = (wave >> 1) * 64, nh = (wave & 1) * 64;
  const int r8 = lane >> 3;        // 0..7: row within wave's staging band
  const int c8 = (lane & 7) ^ r8;  // swizzled global chunk for this lane
  const int mx7 = m & 7;           // fragment-read swizzle key
  f32x4 acc[4][4];
#pragma unroll
  for (int i = 0; i < 4; ++i)
#pragma unroll
    for (int j = 0; j < 4; ++j) acc[i][j] = (f32x4){0.f, 0.f, 0.f, 0.f};

  for (int k0 = 0; k0 < ND; k0 += 64) {
    __syncthreads();  // prior iteration's fragment readers done
#pragma unroll
    for (int i = 0; i < 4; ++i) {
      int row = i * 32 + wave * 8 + r8;
      dma16(A + (size_t)(m0 + row) * ND + k0 + c8 * 8,
            As + (i * 256 + wave * 64) * 8);
      dma16(Bt + (size_t)(n0 + row) * ND + k0 + c8 * 8,
            Bs + (i * 256 + wave * 64) * 8);
    }
    __syncthreads();  // drains vmcnt: all DMA visible
    bf16x8 af[4][2], bf[4][2];
#pragma unroll
    for (int mt = 0; mt < 4; ++mt)
#pragma unroll
      for (int kc = 0; kc < 2; ++kc)
        af[mt][kc] = *(const bf16x8*)(As + (mh + mt * 16 + m) * 64 +
                                      ((kc * 4 + quad) ^ mx7) * 8);
#pragma unroll
    for (int nt = 0; nt < 4; ++nt)
#pragma unroll
      for (int kc = 0; kc < 2; ++kc)
        bf[nt][kc] = *(const bf16x8*)(Bs + (nh + nt * 16 + m) * 64 +
                                      ((kc * 4 + quad) ^ mx7) * 8);
#pragma unroll
    for (int mt = 0; mt < 4; ++mt)
#pragma unroll
      for (int nt = 0; nt < 4; ++nt)
#pragma unroll
        for (int kc = 0; kc < 2; ++kc)
          acc[mt][nt] = __builtin_amdgcn_mfma_f32_16x16x32_bf16(
              af[mt][kc], bf[nt][kc], acc[mt][nt], 0, 0, 0);
  }
  if (mode == 2) {
    // V^T scatter: value at (token row, channel col) -> Vt[b][h][d][s]
#pragma unroll
    for (int mt = 0; mt < 4; ++mt)
#pragma unroll
      for (int nt = 0; nt < 4; ++nt) {
        int row0 = m0 + mh + mt * 16 + quad * 4;
        int col = n0 + nh + nt * 16 + m;
        int b_ = row0 >> 11, s_ = row0 & (NS - 1);
        int h_ = col >> 6, d_ = col & (DEP - 1);
        uint2 p;
        p.x = pk2(acc[mt][nt][0] * alpha, acc[mt][nt][1] * alpha);
        p.y = pk2(acc[mt][nt][2] * alpha, acc[mt][nt][3] * alpha);
        *(uint2*)(Cout + (size_t)((b_ * NH + h_) * DEP + d_) * NS + s_) = p;
      }
  } else {
#pragma unroll
    for (int mt = 0; mt < 4; ++mt)
#pragma unroll
      for (int nt = 0; nt < 4; ++nt)
#pragma unroll
        for (int r = 0; r < 4; ++r) {
          int row = m0 + mh + mt * 16 + quad * 4 + r;
          int col = n0 + nh + nt * 16 + m;
          Cout[(size_t)row * ND + col] = f2b(acc[mt][nt][r] * alpha);
        }
  }
}

__global__ __launch_bounds__(256) void qkv_gemm(
    const short* __restrict__ xb, const short* __restrict__ yb,
    const short* __restrict__ Wqt, const short* __restrict__ Wkt,
    const short* __restrict__ Wvt, short* __restrict__ Qb,
    short* __restrict__ Kb, short* __restrict__ Vtb) {
  if (blockIdx.z == 0)
    gemm128(xb, Wqt, Qb, 1, QSCALE);  // scale + log2e folded into Q
  else if (blockIdx.z == 1)
    gemm128(yb, Wkt, Kb, 1, 1.0f);
  else
    gemm128(yb, Wvt, Vtb, 2, 1.0f);
}

// ---------------------------------------------------------------------------
// Output GEMM: 128x64 tile, BK=64, double-buffered DMA, swizzled LDS,
// fp32 row-major out.  Grid 512 = 2 blocks/CU.
// ---------------------------------------------------------------------------
__global__ __launch_bounds__(256) void out_gemm(const short* __restrict__ A,
                                                const short* __restrict__ Bt,
                                                float* __restrict__ Cout) {
  __shared__ short As[2][128 * 64];
  __shared__ short Bs[2][64 * 64];
  const int t = threadIdx.x;
  const int wave = t >> 6, lane = t & 63;
  const int m = lane & 15, quad = lane >> 4;
  const int m0 = blockIdx.y * 128, n0 = blockIdx.x * 64;
  const int mh = (wave >> 1) * 64, nh = (wave & 1) * 32;
  const int r8 = lane >> 3;
  const int c8 = (lane & 7) ^ r8;
  const int mx7 = m & 7;
  f32x4 acc[4][2];
#pragma unroll
  for (int i = 0; i < 4; ++i)
#pragma unroll
    for (int j = 0; j < 2; ++j) acc[i][j] = (f32x4){0.f, 0.f, 0.f, 0.f};

#pragma unroll
  for (int i = 0; i < 4; ++i)
    dma16(A + (size_t)(m0 + i * 32 + wave * 8 + r8) * ND + c8 * 8,
          As[0] + (i * 256 + wave * 64) * 8);
#pragma unroll
  for (int i = 0; i < 2; ++i)
    dma16(Bt + (size_t)(n0 + i * 32 + wave * 8 + r8) * ND + c8 * 8,
          Bs[0] + (i * 256 + wave * 64) * 8);

  int buf = 0;
  for (int k0 = 0; k0 < ND; k0 += 64, buf ^= 1) {
    __syncthreads();
    if (k0 + 64 < ND) {
#pragma unroll
      for (int i = 0; i < 4; ++i)
        dma16(A + (size_t)(m0 + i * 32 + wave * 8 + r8) * ND + k0 + 64 + c8 * 8,
              As[buf ^ 1] + (i * 256 + wave * 64) * 8);
#pragma unroll
      for (int i = 0; i < 2; ++i)
        dma16(Bt + (size_t)(n0 + i * 32 + wave * 8 + r8) * ND + k0 + 64 +
                  c8 * 8,
              Bs[buf ^ 1] + (i * 256 + wave * 64) * 8);
    }
    bf16x8 af[4][2], bf[2][2];
#pragma unroll
    for (int mt = 0; mt < 4; ++mt)
#pragma unroll
      for (int kc = 0; kc < 2; ++kc)
        af[mt][kc] = *(const bf16x8*)(As[buf] + (mh + mt * 16 + m) * 64 +
                                      ((kc * 4 + quad) ^ mx7) * 8);
#pragma unroll
    for (int nt = 0; nt < 2; ++nt)
#pragma unroll
      for (int kc = 0; kc < 2; ++kc)
        bf[nt][kc] = *(const bf16x8*)(Bs[buf] + (nh + nt * 16 + m) * 64 +
                                      ((kc * 4 + quad) ^ mx7) * 8);
#pragma unroll
    for (int mt = 0; mt < 4; ++mt)
#pragma unroll
      for (int nt = 0; nt < 2; ++nt)
#pragma unroll
        for (int kc = 0; kc < 2; ++kc)
          acc[mt][nt] = __builtin_amdgcn_mfma_f32_16x16x32_bf16(
              af[mt][kc], bf[nt][kc], acc[mt][nt], 0, 0, 0);
  }
#pragma unroll
  for (int mt = 0; mt < 4; ++mt)
#pragma unroll
    for (int nt = 0; nt < 2; ++nt)
#pragma unroll
      for (int r = 0; r < 4; ++r) {
        int row = m0 + mh + mt * 16 + quad * 4 + r;
        int col = n0 + nh + nt * 16 + m;
        Cout[(size_t)row * ND + col] = acc[mt][nt][r];
      }
}

// ---------------------------------------------------------------------------
// Flash attention, S^T formulation, 32x32x16 MFMA, in-register softmax,
// IN-BLOCK kv-split x2 (8 waves: 0-3 kv[0,1024), 4-7 kv[1024,2048)).
// pf-PIPELINE: iteration t computes QK(t) [MFMA], then PV(t-1) [independent
// MFMA from the previous tile's packed pf regs -- fills the QK->softmax
// dependency gap], then softmax(t)->pf.  Single pf[4] set (16 VGPRs
// carried): PV-before-SM program order honors the WAR hazard.
// __launch_bounds__(512, 2): hipcc treats arg2 CUDA-style as BLOCKS/CU;
// r4/r5's (512,4) capped VGPR at 64 (32 waves/CU) and spilled the pipeline
// state to scratch (155/78 MB WRITE_SIZE).  LDS (64 KB) caps residency at
// 2 blocks/CU anyway, so 2 is the right target -> 128 VGPR budget.
// Slot schedule: at iter t issue K(t+1)->Ks[(t+1)&1], V(t)->Vts[t&1];
// QK(t) reads Ks[t&1]; PV(t-1) reads Vts[(t-1)&1].  No collisions; all
// cross-iteration reuse separated by the per-iteration barrier.
// Max-free softmax partials combine exactly in LDS: O=(O0+O1)/(l0+l1).
// ---------------------------------------------------------------------------
__global__ __launch_bounds__(512, 2) void attn_mfma(
    const short* __restrict__ Qb, const short* __restrict__ Kb,
    const short* __restrict__ Vtb, short* __restrict__ Ob) {
  __shared__ short Ks[2][2][64 * 64];   // [zh][slot][kv][d] swizzled
  __shared__ short Vts[2][2][64 * 64];  // [zh][slot][d][kv] swizzled
  const int t = threadIdx.x;
  const int wave = t >> 6, lane = t & 63;
  const int zh = wave >> 2, wl = wave & 3;  // kv-half, q-subtile
  const int l31 = lane & 31, hi = lane >> 5;
  const int sw = lane & 7;  // fragment-read swizzle key (row&7 == lane&7)
  const int bh = blockIdx.y, b = bh >> 3, h = bh & 7;
  const int q0 = blockIdx.x * 128 + wl * 32;
  const int kvb = zh * KVHALF;
  const size_t rowb = (size_t)b * NS;
  const short* Vtbase = Vtb + (size_t)(bh * DEP) * NS;
  const int r8 = lane >> 3;
  const int c8 = (lane & 7) ^ r8;

  // Q fragments (B-operand): col=q=l31, k(d) = dc*16 + hi*8 + j
  bf16x8 qf[4];
#pragma unroll
  for (int dc = 0; dc < 4; ++dc)
    qf[dc] = *(const bf16x8*)(Qb + (rowb + q0 + l31) * ND + h * DEP + dc * 16 +
                              hi * 8);

  // loop-invariant zero C-operand (St init without per-iter v_movs)
  f32x16 kzero;
#pragma unroll
  for (int i = 0; i < 16; ++i) kzero[i] = 0.f;

  float l_ = 0.0f;
  f32x16 Ot[2];
#pragma unroll
  for (int dt = 0; dt < 2; ++dt)
#pragma unroll
    for (int i = 0; i < 16; ++i) Ot[dt][i] = 0.f;

  f32x16 St0, St1;  // current tile S^T (dies within the iteration)
  bf16x8 pf[4];     // packed P^T fragments, carried across the barrier

#define KDMA(tt)                                                          \
  {                                                                       \
    _Pragma("unroll") for (int i_ = 0; i_ < 2; ++i_) {                    \
      int row_ = i_ * 32 + wl * 8 + r8;                                   \
      dma16(Kb + (rowb + kvb + (tt) * 64 + row_) * ND + h * DEP + c8 * 8, \
            &Ks[zh][(tt) & 1][(i_ * 256 + wl * 64) * 8]);                 \
    }                                                                     \
  }
#define VDMA(tt)                                                       \
  {                                                                    \
    _Pragma("unroll") for (int i_ = 0; i_ < 2; ++i_) {                 \
      int row_ = i_ * 32 + wl * 8 + r8;                                \
      dma16(Vtbase + (size_t)row_ * NS + kvb + (tt) * 64 + c8 * 8,     \
            &Vts[zh][(tt) & 1][(i_ * 256 + wl * 64) * 8]);             \
    }                                                                  \
  }
// QK(tt): St0/St1 = K-tile x Q (S^T: kv = kt*32+row, q = col = l31)
#define QKH(SD, KT, kb_)                                                     \
  {                                                                          \
    bf16x8 kf_;                                                              \
    kf_ = *(const bf16x8*)((kb_) + ((KT)*32 + l31) * 64 + ((0 + hi) ^ sw) * 8); \
    SD = __builtin_amdgcn_mfma_f32_32x32x16_bf16(kf_, qf[0], kzero, 0, 0, 0); \
    kf_ = *(const bf16x8*)((kb_) + ((KT)*32 + l31) * 64 + ((2 + hi) ^ sw) * 8); \
    SD = __builtin_amdgcn_mfma_f32_32x32x16_bf16(kf_, qf[1], SD, 0, 0, 0);   \
    kf_ = *(const bf16x8*)((kb_) + ((KT)*32 + l31) * 64 + ((4 + hi) ^ sw) * 8); \
    SD = __builtin_amdgcn_mfma_f32_32x32x16_bf16(kf_, qf[2], SD, 0, 0, 0);   \
    kf_ = *(const bf16x8*)((kb_) + ((KT)*32 + l31) * 64 + ((6 + hi) ^ sw) * 8); \
    SD = __builtin_amdgcn_mfma_f32_32x32x16_bf16(kf_, qf[3], SD, 0, 0, 0);   \
  }
#define QK(tt)                                  \
  {                                             \
    const short* kb_ = &Ks[zh][(tt) & 1][0];    \
    __builtin_amdgcn_s_setprio(1);              \
    QKH(St0, 0, kb_);                           \
    QKH(St1, 1, kb_);                           \
    __builtin_amdgcn_s_setprio(0);              \
  }
// softmax slice: exp2 on 8 St values, pack to bf16, permlane-redistribute.
// St reg r: kv = kt*32 + (r&3) + 8*(r>>2) + 4*hi; B-frag slice s elem j =
// P[s*16 + hi*8 + j][q].
#define SM_SLICE(SS, BASE, SIDX)                                             \
  {                                                                          \
    float E0 = __builtin_amdgcn_exp2f(SS[(BASE) + 0]);                       \
    float E1 = __builtin_amdgcn_exp2f(SS[(BASE) + 1]);                       \
    float E2 = __builtin_amdgcn_exp2f(SS[(BASE) + 2]);                       \
    float E3 = __builtin_amdgcn_exp2f(SS[(BASE) + 3]);                       \
    float E4 = __builtin_amdgcn_exp2f(SS[(BASE) + 4]);                       \
    float E5 = __builtin_amdgcn_exp2f(SS[(BASE) + 5]);                       \
    float E6 = __builtin_amdgcn_exp2f(SS[(BASE) + 6]);                       \
    float E7 = __builtin_amdgcn_exp2f(SS[(BASE) + 7]);                       \
    l_ += ((E0 + E1) + (E2 + E3)) + ((E4 + E5) + (E6 + E7));                 \
    unsigned A0 = pk2(E0, E1), A1 = pk2(E2, E3);                             \
    unsigned A2 = pk2(E4, E5), A3 = pk2(E6, E7);                             \
    auto r02 =                                                               \
        __builtin_amdgcn_permlane32_swap((int)A0, (int)A2, false, false);    \
    auto r13 =                                                               \
        __builtin_amdgcn_permlane32_swap((int)A1, (int)A3, false, false);    \
    union { bf16x8 v; int u[4]; } pu_;                                       \
    pu_.u[0] = r02[0]; pu_.u[1] = r13[0]; pu_.u[2] = r02[1];                 \
    pu_.u[3] = r13[1];                                                       \
    pf[SIDX] = pu_.v;                                                        \
  }
#define SM()               \
  SM_SLICE(St0, 0, 0)      \
  SM_SLICE(St0, 8, 1)      \
  SM_SLICE(St1, 0, 2)      \
  SM_SLICE(St1, 8, 3)
// PV(tt): Ot^T[dt] += V^T[d, kv-slice] * P^T[kv-slice, q] (reads pf)
#define PV(tt)                                                             \
  {                                                                        \
    const short* vb_ = &Vts[zh][(tt) & 1][0];                              \
    __builtin_amdgcn_s_setprio(1);                                         \
    _Pragma("unroll") for (int dt_ = 0; dt_ < 2; ++dt_) {                  \
      _Pragma("unroll") for (int s_ = 0; s_ < 4; ++s_) {                   \
        bf16x8 vf_ = *(const bf16x8*)(vb_ + (dt_ * 32 + l31) * 64 +        \
                                      ((s_ * 2 + hi) ^ sw) * 8);           \
        Ot[dt_] = __builtin_amdgcn_mfma_f32_32x32x16_bf16(vf_, pf[s_],     \
                                                          Ot[dt_], 0, 0, 0); \
      }                                                                    \
    }                                                                      \
    __builtin_amdgcn_s_setprio(0);                                         \
  }

  // prologue
  KDMA(0);
  __syncthreads();  // K(0) landed
  KDMA(1);
  VDMA(0);
  QK(0);
  SM();  // t=0: no PV yet
#pragma unroll 1
  for (int tt = 1; tt < 16; ++tt) {
    __syncthreads();  // K(tt), V(tt-1) landed; prior slot readers done
    if (tt < 15) KDMA(tt + 1);
    VDMA(tt);
    QK(tt);       // Ks slot tt&1
    PV(tt - 1);   // Vts slot (tt-1)&1; independent MFMA under QK->SM gap
    SM();         // overwrites pf (after PV consumed it)
  }
  __syncthreads();  // V(15) landed
  PV(15);

  // per-wave denominator partial: lane l and l^32 hold complementary kv sets
  l_ += __shfl_xor(l_, 32, 64);

  // cross-half combine in LDS (aliased over dead K/V staging buffers).
  __syncthreads();  // all K/V fragment reads of the last tile complete
  float* Ox = (float*)Ks;   // [4][64][32] fp32 = 32 KB
  float* lx = (float*)Vts;  // [4][32] fp32
  if (zh == 1) {
#pragma unroll
    for (int dt = 0; dt < 2; ++dt)
#pragma unroll
      for (int r = 0; r < 16; ++r) {
        int d = dt * 32 + (r & 3) + 8 * (r >> 2) + 4 * hi;
        Ox[(wl * 64 + d) * 32 + l31] = Ot[dt][r];
      }
    if (lane < 32) lx[wl * 32 + l31] = l_;
  }
  __syncthreads();
  if (zh == 0) {
    float linv = 1.0f / (l_ + lx[wl * 32 + l31]);
    size_t row = rowb + q0 + l31;
    // Ot reg r (tile dt): d = dt*32 + (r&3) + 8*(r>>2) + 4*hi -> 8B stores
#pragma unroll
    for (int dt = 0; dt < 2; ++dt)
#pragma unroll
      for (int g = 0; g < 4; ++g) {
        int d0 = dt * 32 + g * 8 + hi * 4;
        float o[4];
#pragma unroll
        for (int jj = 0; jj < 4; ++jj)
          o[jj] = Ot[dt][g * 4 + jj] + Ox[(wl * 64 + d0 + jj) * 32 + l31];
        uint2 pk;
        pk.x = pk2(o[0] * linv, o[1] * linv);
        pk.y = pk2(o[2] * linv, o[3] * linv);
        *(uint2*)(Ob + row * ND + h * DEP + d0) = pk;
      }
  }
#undef KDMA
#undef VDMA
#undef QKH
#undef QK
#undef SM_SLICE
#undef SM
#undef PV
}

// ---------------------------------------------------------------------------
extern "C" void kernel_launch(void* const* d_in, const int* in_sizes, int n_in,
                              void* d_out, int out_size, void* d_ws,
                              size_t ws_size, hipStream_t stream) {
  const float* x = (const float*)d_in[0];
  const float* y = (const float*)d_in[1];
  const float* Wq = (const float*)d_in[2];
  const float* Wk = (const float*)d_in[3];
  const float* Wv = (const float*)d_in[4];
  const float* Wo = (const float*)d_in[5];
  float* out = (float*)d_out;

  const size_t mat = (size_t)NB * NS * ND;
  const size_t wsz = (size_t)ND * ND;
  short* xb = (short*)d_ws;
  short* yb = xb + mat;
  short* Wqt = yb + mat;
  short* Wkt = Wqt + wsz;
  short* Wvt = Wkt + wsz;
  short* Wot = Wvt + wsz;
  short* Qb = Wot + wsz;
  short* Kb = Qb + mat;
  short* Vtb = Kb + mat;
  short* attnb = xb;  // reuse: xb dead after QKV GEMM

  prep<<<dim3(mat / 1024, 3), 256, 0, stream>>>(x, y, Wq, Wk, Wv, Wo, xb, yb,
                                                Wqt, Wkt, Wvt, Wot);
  qkv_gemm<<<dim3(ND / 128, (NB * NS) / 128, 3), 256, 0, stream>>>(
      xb, yb, Wqt, Wkt, Wvt, Qb, Kb, Vtb);
  attn_mfma<<<dim3(NS / 128, NB * NH), 512, 0, stream>>>(Qb, Kb, Vtb, attnb);
  out_gemm<<<dim3(ND / 64, (NB * NS) / 128), 256, 0, stream>>>(attnb, Wot,
                                                               out);
}

// Round 7
// 184.092 us; speedup vs baseline: 1.2099x; 1.0807x over previous
//
#include <hip/hip_runtime.h>
#include <hip/hip_bf16.h>
#include <math.h>
#include <stdint.h>

#define NB 4
#define NS 2048
#define ND 512
#define NH 8
#define DEP 64
#define KVHALF (NS / 2)

typedef __attribute__((ext_vector_type(8))) short bf16x8;
typedef __attribute__((ext_vector_type(4))) short bf16x4;
typedef __attribute__((ext_vector_type(4))) float f32x4;
typedef __attribute__((ext_vector_type(16))) float f32x16;

#define QSCALE 0.18033688011112042f  // DEPTH^-0.5 * log2(e): softmax in exp2

__device__ __forceinline__ short f2b(float f) {
  unsigned u = __float_as_uint(f);
  u += 0x7FFF + ((u >> 16) & 1);  // RNE
  return (short)(u >> 16);
}
__device__ __forceinline__ unsigned pk2(float a, float b) {
  union { __hip_bfloat162 h; unsigned u; } c;
  c.h = __float22bfloat162_rn(float2{a, b});
  return c.u;
}
// async 16B global->LDS DMA; LDS dest is wave-uniform base + lane*16
__device__ __forceinline__ void dma16(const void* g, void* l) {
  __builtin_amdgcn_global_load_lds(
      (const __attribute__((address_space(1))) void*)g,
      (__attribute__((address_space(3))) void*)l, 16, 0, 0);
}

// ---------------------------------------------------------------------------
// prep: one launch does BOTH input casts and all 4 weight transposes.
// grid (4096, 3): y=0 cast x, y=1 cast y, y=2 (x<256) transpose W0..W3.
// ---------------------------------------------------------------------------
__global__ __launch_bounds__(256) void prep(
    const float* __restrict__ x, const float* __restrict__ y,
    const float* __restrict__ W0, const float* __restrict__ W1,
    const float* __restrict__ W2, const float* __restrict__ W3,
    short* __restrict__ xb, short* __restrict__ yb, short* __restrict__ T0,
    short* __restrict__ T1, short* __restrict__ T2, short* __restrict__ T3) {
  const int t = threadIdx.x;
  if (blockIdx.y < 2) {
    const float* src = blockIdx.y ? y : x;
    short* dst = blockIdx.y ? yb : xb;
    size_t i = ((size_t)blockIdx.x * 256 + t) * 4;
    float4 v = *(const float4*)(src + i);
    bf16x4 o;
    o[0] = f2b(v.x); o[1] = f2b(v.y); o[2] = f2b(v.z); o[3] = f2b(v.w);
    *(bf16x4*)(dst + i) = o;
    return;
  }
  const int bx = blockIdx.x;
  if (bx >= 256) return;
  const int wj = bx >> 6, rem = bx & 63;
  const float* W = wj == 0 ? W0 : wj == 1 ? W1 : wj == 2 ? W2 : W3;
  short* T = wj == 0 ? T0 : wj == 1 ? T1 : wj == 2 ? T2 : T3;
  __shared__ float tile[64][65];
  const int k0 = (rem >> 3) * 64, n0 = (rem & 7) * 64;
#pragma unroll
  for (int i = 0; i < 4; ++i) {
    int r = (t >> 4) + i * 16;
    int c = (t & 15) * 4;
    float4 v = *(const float4*)&W[(size_t)(k0 + r) * ND + n0 + c];
    tile[r][c] = v.x; tile[r][c + 1] = v.y;
    tile[r][c + 2] = v.z; tile[r][c + 3] = v.w;
  }
  __syncthreads();
#pragma unroll
  for (int i = 0; i < 4; ++i) {
    int n = (t >> 4) + i * 16;
    int kc = (t & 15) * 4;
    bf16x4 o;
#pragma unroll
    for (int j = 0; j < 4; ++j) o[j] = f2b(tile[kc + j][n]);
    *(bf16x4*)&T[(size_t)(n0 + n) * ND + k0 + kc] = o;
  }
}

// ---------------------------------------------------------------------------
// QKV GEMM: 128x128 tile, 4 waves each 64x64 (acc 4x4), BK=64, single-buffer
// DMA staging (m97 2-barrier), XOR-swizzled LDS (pitch 64, chunk ^= row&7).
// mode 1: bf16 row-major out; 2: bf16 V^T out via LDS-transposed COALESCED
// epilogue (old path: per-lane 8B scatter at 4KB stride = 64 transactions
// per store instr + ~4x write-sector amplification on 8.4 MB).
// ---------------------------------------------------------------------------
__device__ __forceinline__ void gemm128(const short* __restrict__ A,
                                        const short* __restrict__ Bt,
                                        short* __restrict__ Cout, int mode,
                                        float alpha) {
  __shared__ short As[128 * 64];
  __shared__ short Bs[128 * 64];
  __shared__ short Tb[64 * 128];  // mode-2 transpose staging [c][r], 16 KB
  const int t = threadIdx.x;
  const int wave = t >> 6, lane = t & 63;
  const int m = lane & 15, quad = lane >> 4;
  const int m0 = blockIdx.y * 128, n0 = blockIdx.x * 128;
  const int mh = (wave >> 1) * 64, nh = (wave & 1) * 64;
  const int r8 = lane >> 3;        // 0..7: row within wave's staging band
  const int c8 = (lane & 7) ^ r8;  // swizzled global chunk for this lane
  const int mx7 = m & 7;           // fragment-read swizzle key
  f32x4 acc[4][4];
#pragma unroll
  for (int i = 0; i < 4; ++i)
#pragma unroll
    for (int j = 0; j < 4; ++j) acc[i][j] = (f32x4){0.f, 0.f, 0.f, 0.f};

  for (int k0 = 0; k0 < ND; k0 += 64) {
    __syncthreads();  // prior iteration's fragment readers done
#pragma unroll
    for (int i = 0; i < 4; ++i) {
      int row = i * 32 + wave * 8 + r8;
      dma16(A + (size_t)(m0 + row) * ND + k0 + c8 * 8,
            As + (i * 256 + wave * 64) * 8);
      dma16(Bt + (size_t)(n0 + row) * ND + k0 + c8 * 8,
            Bs + (i * 256 + wave * 64) * 8);
    }
    __syncthreads();  // drains vmcnt: all DMA visible
    bf16x8 af[4][2], bf[4][2];
#pragma unroll
    for (int mt = 0; mt < 4; ++mt)
#pragma unroll
      for (int kc = 0; kc < 2; ++kc)
        af[mt][kc] = *(const bf16x8*)(As + (mh + mt * 16 + m) * 64 +
                                      ((kc * 4 + quad) ^ mx7) * 8);
#pragma unroll
    for (int nt = 0; nt < 4; ++nt)
#pragma unroll
      for (int kc = 0; kc < 2; ++kc)
        bf[nt][kc] = *(const bf16x8*)(Bs + (nh + nt * 16 + m) * 64 +
                                      ((kc * 4 + quad) ^ mx7) * 8);
#pragma unroll
    for (int mt = 0; mt < 4; ++mt)
#pragma unroll
      for (int nt = 0; nt < 4; ++nt)
#pragma unroll
        for (int kc = 0; kc < 2; ++kc)
          acc[mt][nt] = __builtin_amdgcn_mfma_f32_16x16x32_bf16(
              af[mt][kc], bf[nt][kc], acc[mt][nt], 0, 0, 0);
  }
  if (mode == 2) {
    // V^T epilogue: two 64-col passes through Tb[c][r], then each thread
    // writes 64 B of s-contiguous V^T (256 B contiguous per channel row).
    const int h0 = n0 >> 6;                        // n0 is 128-aligned
    const int b_ = m0 >> 11, s0g = m0 & (NS - 1);  // 128-row tile: one b
#pragma unroll
    for (int p = 0; p < 2; ++p) {
      __syncthreads();  // Tb free (p0: main loop done; p1: p0 readers done)
      if ((wave & 1) == p) {
        // wave's cols nh + nt*16 + m, nh == p*64 -> local c = nt*16 + m
#pragma unroll
        for (int mt = 0; mt < 4; ++mt)
#pragma unroll
          for (int nt = 0; nt < 4; ++nt)
#pragma unroll
            for (int r = 0; r < 4; ++r)
              Tb[(nt * 16 + m) * 128 + mh + mt * 16 + quad * 4 + r] =
                  f2b(acc[mt][nt][r] * alpha);
      }
      __syncthreads();
      {
        int c = t >> 2, sc = (t & 3) * 32;  // c: 0..63, sc: 0/32/64/96
        int gcol = p * 64 + c;
        int h_ = h0 + (gcol >> 6), d_ = gcol & (DEP - 1);
        short* dst =
            Cout + (size_t)((b_ * NH + h_) * DEP + d_) * NS + s0g + sc;
        const short* src = Tb + c * 128 + sc;
#pragma unroll
        for (int i = 0; i < 4; ++i)
          *(bf16x8*)(dst + i * 8) = *(const bf16x8*)(src + i * 8);
      }
    }
  } else {
#pragma unroll
    for (int mt = 0; mt < 4; ++mt)
#pragma unroll
      for (int nt = 0; nt < 4; ++nt)
#pragma unroll
        for (int r = 0; r < 4; ++r) {
          int row = m0 + mh + mt * 16 + quad * 4 + r;
          int col = n0 + nh + nt * 16 + m;
          Cout[(size_t)row * ND + col] = f2b(acc[mt][nt][r] * alpha);
        }
  }
}

__global__ __launch_bounds__(256) void qkv_gemm(
    const short* __restrict__ xb, const short* __restrict__ yb,
    const short* __restrict__ Wqt, const short* __restrict__ Wkt,
    const short* __restrict__ Wvt, short* __restrict__ Qb,
    short* __restrict__ Kb, short* __restrict__ Vtb) {
  if (blockIdx.z == 0)
    gemm128(xb, Wqt, Qb, 1, QSCALE);  // scale + log2e folded into Q
  else if (blockIdx.z == 1)
    gemm128(yb, Wkt, Kb, 1, 1.0f);
  else
    gemm128(yb, Wvt, Vtb, 2, 1.0f);
}

// ---------------------------------------------------------------------------
// Output GEMM: 128x64 tile, BK=64, double-buffered DMA, swizzled LDS,
// fp32 row-major out.  Grid 512 = 2 blocks/CU.
// ---------------------------------------------------------------------------
__global__ __launch_bounds__(256) void out_gemm(const short* __restrict__ A,
                                                const short* __restrict__ Bt,
                                                float* __restrict__ Cout) {
  __shared__ short As[2][128 * 64];
  __shared__ short Bs[2][64 * 64];
  const int t = threadIdx.x;
  const int wave = t >> 6, lane = t & 63;
  const int m = lane & 15, quad = lane >> 4;
  const int m0 = blockIdx.y * 128, n0 = blockIdx.x * 64;
  const int mh = (wave >> 1) * 64, nh = (wave & 1) * 32;
  const int r8 = lane >> 3;
  const int c8 = (lane & 7) ^ r8;
  const int mx7 = m & 7;
  f32x4 acc[4][2];
#pragma unroll
  for (int i = 0; i < 4; ++i)
#pragma unroll
    for (int j = 0; j < 2; ++j) acc[i][j] = (f32x4){0.f, 0.f, 0.f, 0.f};

#pragma unroll
  for (int i = 0; i < 4; ++i)
    dma16(A + (size_t)(m0 + i * 32 + wave * 8 + r8) * ND + c8 * 8,
          As[0] + (i * 256 + wave * 64) * 8);
#pragma unroll
  for (int i = 0; i < 2; ++i)
    dma16(Bt + (size_t)(n0 + i * 32 + wave * 8 + r8) * ND + c8 * 8,
          Bs[0] + (i * 256 + wave * 64) * 8);

  int buf = 0;
  for (int k0 = 0; k0 < ND; k0 += 64, buf ^= 1) {
    __syncthreads();
    if (k0 + 64 < ND) {
#pragma unroll
      for (int i = 0; i < 4; ++i)
        dma16(A + (size_t)(m0 + i * 32 + wave * 8 + r8) * ND + k0 + 64 + c8 * 8,
              As[buf ^ 1] + (i * 256 + wave * 64) * 8);
#pragma unroll
      for (int i = 0; i < 2; ++i)
        dma16(Bt + (size_t)(n0 + i * 32 + wave * 8 + r8) * ND + k0 + 64 +
                  c8 * 8,
              Bs[buf ^ 1] + (i * 256 + wave * 64) * 8);
    }
    bf16x8 af[4][2], bf[2][2];
#pragma unroll
    for (int mt = 0; mt < 4; ++mt)
#pragma unroll
      for (int kc = 0; kc < 2; ++kc)
        af[mt][kc] = *(const bf16x8*)(As[buf] + (mh + mt * 16 + m) * 64 +
                                      ((kc * 4 + quad) ^ mx7) * 8);
#pragma unroll
    for (int nt = 0; nt < 2; ++nt)
#pragma unroll
      for (int kc = 0; kc < 2; ++kc)
        bf[nt][kc] = *(const bf16x8*)(Bs[buf] + (nh + nt * 16 + m) * 64 +
                                      ((kc * 4 + quad) ^ mx7) * 8);
#pragma unroll
    for (int mt = 0; mt < 4; ++mt)
#pragma unroll
      for (int nt = 0; nt < 2; ++nt)
#pragma unroll
        for (int kc = 0; kc < 2; ++kc)
          acc[mt][nt] = __builtin_amdgcn_mfma_f32_16x16x32_bf16(
              af[mt][kc], bf[nt][kc], acc[mt][nt], 0, 0, 0);
  }
#pragma unroll
  for (int mt = 0; mt < 4; ++mt)
#pragma unroll
    for (int nt = 0; nt < 2; ++nt)
#pragma unroll
      for (int r = 0; r < 4; ++r) {
        int row = m0 + mh + mt * 16 + quad * 4 + r;
        int col = n0 + nh + nt * 16 + m;
        Cout[(size_t)row * ND + col] = acc[mt][nt][r];
      }
}

// ---------------------------------------------------------------------------
// Flash attention, S^T formulation, 32x32x16 MFMA, in-register softmax,
// IN-BLOCK kv-split x2: 512 threads = 8 waves; waves 0-3 do kv[0,1024),
// waves 4-7 do kv[1024,2048), each half with private double-buffered K/V LDS
// (64 KB total -> 2 blocks/CU = 4 waves/SIMD).  Max-free softmax partials
// combine exactly in LDS at the end: O = (O0+O1)/(l0+l1).  (r3 body —
// proven 54.4 us; r4-r6 pipeline variants all regressed.)
// ---------------------------------------------------------------------------
__global__ __launch_bounds__(512, 4) void attn_mfma(
    const short* __restrict__ Qb, const short* __restrict__ Kb,
    const short* __restrict__ Vtb, short* __restrict__ Ob) {
  __shared__ short Ks[2][2][64 * 64];   // [zh][buf][kv][d] swizzled
  __shared__ short Vts[2][2][64 * 64];  // [zh][buf][d][kv] swizzled
  const int t = threadIdx.x;
  const int wave = t >> 6, lane = t & 63;
  const int zh = wave >> 2, wl = wave & 3;  // kv-half, q-subtile
  const int l31 = lane & 31, hi = lane >> 5;
  const int sw = lane & 7;  // fragment-read swizzle key (row&7 == lane&7)
  const int bh = blockIdx.y, b = bh >> 3, h = bh & 7;
  const int q0 = blockIdx.x * 128 + wl * 32;
  const int kvb = zh * KVHALF;
  const size_t rowb = (size_t)b * NS;
  const short* Vtbase = Vtb + (size_t)(bh * DEP) * NS;
  const int r8 = lane >> 3;
  const int c8 = (lane & 7) ^ r8;

  // Q fragments (B-operand): col=q=l31, k(d) = dc*16 + hi*8 + j
  bf16x8 qf[4];
#pragma unroll
  for (int dc = 0; dc < 4; ++dc)
    qf[dc] = *(const bf16x8*)(Qb + (rowb + q0 + l31) * ND + h * DEP + dc * 16 +
                              hi * 8);

  // loop-invariant zero C-operand: avoids 32 v_mov per iteration (St init)
  f32x16 kzero;
#pragma unroll
  for (int i = 0; i < 16; ++i) kzero[i] = 0.f;

  float l_ = 0.0f;
  f32x16 Ot[2];
#pragma unroll
  for (int dt = 0; dt < 2; ++dt)
#pragma unroll
    for (int i = 0; i < 16; ++i) Ot[dt][i] = 0.f;

#pragma unroll
  for (int i = 0; i < 2; ++i) {
    int row = i * 32 + wl * 8 + r8;
    dma16(Kb + (rowb + kvb + row) * ND + h * DEP + c8 * 8,
          &Ks[zh][0][(i * 256 + wl * 64) * 8]);
    dma16(Vtbase + (size_t)row * NS + kvb + c8 * 8,
          &Vts[zh][0][(i * 256 + wl * 64) * 8]);
  }

  int buf = 0;
  for (int kv0 = 0; kv0 < KVHALF; kv0 += 64, buf ^= 1) {
    __syncthreads();  // readers of buf done + prefetch DMA (vmcnt) drained
    if (kv0 + 64 < KVHALF) {
#pragma unroll
      for (int i = 0; i < 2; ++i) {
        int row = i * 32 + wl * 8 + r8;
        dma16(Kb + (rowb + kvb + kv0 + 64 + row) * ND + h * DEP + c8 * 8,
              &Ks[zh][buf ^ 1][(i * 256 + wl * 64) * 8]);
        dma16(Vtbase + (size_t)row * NS + kvb + kv0 + 64 + c8 * 8,
              &Vts[zh][buf ^ 1][(i * 256 + wl * 64) * 8]);
      }
    }

    // QK^T: St[kt] = S^T tile (kv = kt*32+row, q = col = l31)
    f32x16 St[2];
#pragma unroll
    for (int kt = 0; kt < 2; ++kt) {
      bf16x8 kf0 = *(const bf16x8*)(&Ks[zh][buf][(kt * 32 + l31) * 64 +
                                                 (hi ^ sw) * 8]);
      St[kt] = __builtin_amdgcn_mfma_f32_32x32x16_bf16(kf0, qf[0], kzero,
                                                       0, 0, 0);
#pragma unroll
      for (int dc = 1; dc < 4; ++dc) {
        bf16x8 kf = *(const bf16x8*)(&Ks[zh][buf][(kt * 32 + l31) * 64 +
                                                  ((dc * 2 + hi) ^ sw) * 8]);
        St[kt] = __builtin_amdgcn_mfma_f32_32x32x16_bf16(kf, qf[dc], St[kt],
                                                         0, 0, 0);
      }
    }

    // softmax (max-free, exp2) + in-register P^T -> B-fragment assembly.
    // St reg r (tile kt): kv = kt*32 + (r&3) + 8*(r>>2) + 4*hi.
    // B-frag slice s needs: elem j = P[kv0 + s*16 + hi*8 + j][q].
    bf16x8 pf[4];
    float rs = 0.f;
#pragma unroll
    for (int s = 0; s < 4; ++s) {
      const int kt = s >> 1, base = (s & 1) * 8;
      float E[8];
#pragma unroll
      for (int j = 0; j < 8; ++j) {
        E[j] = __builtin_amdgcn_exp2f(St[kt][base + j]);
      }
      rs += ((E[0] + E[1]) + (E[2] + E[3])) + ((E[4] + E[5]) + (E[6] + E[7]));
      unsigned A0 = pk2(E[0], E[1]), A1 = pk2(E[2], E[3]);
      unsigned A2 = pk2(E[4], E[5]), A3 = pk2(E[6], E[7]);
      // swap: out0 = [a.lo | b.lo], out1 = [a.hi | b.hi]
      auto r02 =
          __builtin_amdgcn_permlane32_swap((int)A0, (int)A2, false, false);
      auto r13 =
          __builtin_amdgcn_permlane32_swap((int)A1, (int)A3, false, false);
      union { bf16x8 v; int u[4]; } pu;
      pu.u[0] = r02[0]; pu.u[1] = r13[0]; pu.u[2] = r02[1]; pu.u[3] = r13[1];
      pf[s] = pu.v;
    }
    l_ += rs;

    // PV: Ot^T[dt] += V^T[d, kv-slice] * P^T[kv-slice, q]
#pragma unroll
    for (int dt = 0; dt < 2; ++dt)
#pragma unroll
      for (int s = 0; s < 4; ++s) {
        bf16x8 vf = *(const bf16x8*)(&Vts[zh][buf][(dt * 32 + l31) * 64 +
                                                   ((s * 2 + hi) ^ sw) * 8]);
        Ot[dt] = __builtin_amdgcn_mfma_f32_32x32x16_bf16(vf, pf[s], Ot[dt],
                                                         0, 0, 0);
      }
  }

  // per-wave denominator partial: lane l and l^32 hold complementary kv sets
  l_ += __shfl_xor(l_, 32, 64);

  // cross-half combine in LDS (aliased over dead K/V staging buffers).
  __syncthreads();  // all K/V fragment reads of the last tile complete
  float* Ox = (float*)Ks;   // [4][64][32] fp32 = 32 KB
  float* lx = (float*)Vts;  // [4][32] fp32
  if (zh == 1) {
#pragma unroll
    for (int dt = 0; dt < 2; ++dt)
#pragma unroll
      for (int r = 0; r < 16; ++r) {
        int d = dt * 32 + (r & 3) + 8 * (r >> 2) + 4 * hi;
        Ox[(wl * 64 + d) * 32 + l31] = Ot[dt][r];
      }
    if (lane < 32) lx[wl * 32 + l31] = l_;
  }
  __syncthreads();
  if (zh == 0) {
    float linv = 1.0f / (l_ + lx[wl * 32 + l31]);
    size_t row = rowb + q0 + l31;
    // Ot reg r (tile dt): d = dt*32 + (r&3) + 8*(r>>2) + 4*hi -> 8B stores
#pragma unroll
    for (int dt = 0; dt < 2; ++dt)
#pragma unroll
      for (int g = 0; g < 4; ++g) {
        int d0 = dt * 32 + g * 8 + hi * 4;
        float o[4];
#pragma unroll
        for (int j = 0; j < 4; ++j)
          o[j] = Ot[dt][g * 4 + j] + Ox[(wl * 64 + d0 + j) * 32 + l31];
        uint2 pk;
        pk.x = pk2(o[0] * linv, o[1] * linv);
        pk.y = pk2(o[2] * linv, o[3] * linv);
        *(uint2*)(Ob + row * ND + h * DEP + d0) = pk;
      }
  }
}

// ---------------------------------------------------------------------------
extern "C" void kernel_launch(void* const* d_in, const int* in_sizes, int n_in,
                              void* d_out, int out_size, void* d_ws,
                              size_t ws_size, hipStream_t stream) {
  const float* x = (const float*)d_in[0];
  const float* y = (const float*)d_in[1];
  const float* Wq = (const float*)d_in[2];
  const float* Wk = (const float*)d_in[3];
  const float* Wv = (const float*)d_in[4];
  const float* Wo = (const float*)d_in[5];
  float* out = (float*)d_out;

  const size_t mat = (size_t)NB * NS * ND;
  const size_t wsz = (size_t)ND * ND;
  short* xb = (short*)d_ws;
  short* yb = xb + mat;
  short* Wqt = yb + mat;
  short* Wkt = Wqt + wsz;
  short* Wvt = Wkt + wsz;
  short* Wot = Wvt + wsz;
  short* Qb = Wot + wsz;
  short* Kb = Qb + mat;
  short* Vtb = Kb + mat;
  short* attnb = xb;  // reuse: xb dead after QKV GEMM

  prep<<<dim3(mat / 1024, 3), 256, 0, stream>>>(x, y, Wq, Wk, Wv, Wo, xb, yb,
                                                Wqt, Wkt, Wvt, Wot);
  qkv_gemm<<<dim3(ND / 128, (NB * NS) / 128, 3), 256, 0, stream>>>(
      xb, yb, Wqt, Wkt, Wvt, Qb, Kb, Vtb);
  attn_mfma<<<dim3(NS / 128, NB * NH), 512, 0, stream>>>(Qb, Kb, Vtb, attnb);
  out_gemm<<<dim3(ND / 64, (NB * NS) / 128), 256, 0, stream>>>(attnb, Wot,
                                                               out);
}

// Round 8
// 182.000 us; speedup vs baseline: 1.2238x; 1.0115x over previous
//
#include <hip/hip_runtime.h>
#include <hip/hip_bf16.h>
#include <math.h>
#include <stdint.h>

#define NB 4
#define NS 2048
#define ND 512
#define NH 8
#define DEP 64
#define KVHALF (NS / 2)

typedef __attribute__((ext_vector_type(8))) short bf16x8;
typedef __attribute__((ext_vector_type(4))) short bf16x4;
typedef __attribute__((ext_vector_type(4))) float f32x4;
typedef __attribute__((ext_vector_type(16))) float f32x16;

#define QSCALE 0.18033688011112042f  // DEPTH^-0.5 * log2(e): softmax in exp2

__device__ __forceinline__ short f2b(float f) {
  unsigned u = __float_as_uint(f);
  u += 0x7FFF + ((u >> 16) & 1);  // RNE
  return (short)(u >> 16);
}
__device__ __forceinline__ unsigned pk2(float a, float b) {
  union { __hip_bfloat162 h; unsigned u; } c;
  c.h = __float22bfloat162_rn(float2{a, b});
  return c.u;
}
// async 16B global->LDS DMA; LDS dest is wave-uniform base + lane*16
__device__ __forceinline__ void dma16(const void* g, void* l) {
  __builtin_amdgcn_global_load_lds(
      (const __attribute__((address_space(1))) void*)g,
      (__attribute__((address_space(3))) void*)l, 16, 0, 0);
}

// ---------------------------------------------------------------------------
// prep: one launch does BOTH input casts and all 4 weight transposes.
// grid (4096, 3): y=0 cast x, y=1 cast y, y=2 (x<256) transpose W0..W3.
// ---------------------------------------------------------------------------
__global__ __launch_bounds__(256) void prep(
    const float* __restrict__ x, const float* __restrict__ y,
    const float* __restrict__ W0, const float* __restrict__ W1,
    const float* __restrict__ W2, const float* __restrict__ W3,
    short* __restrict__ xb, short* __restrict__ yb, short* __restrict__ T0,
    short* __restrict__ T1, short* __restrict__ T2, short* __restrict__ T3) {
  const int t = threadIdx.x;
  if (blockIdx.y < 2) {
    const float* src = blockIdx.y ? y : x;
    short* dst = blockIdx.y ? yb : xb;
    size_t i = ((size_t)blockIdx.x * 256 + t) * 4;
    float4 v = *(const float4*)(src + i);
    bf16x4 o;
    o[0] = f2b(v.x); o[1] = f2b(v.y); o[2] = f2b(v.z); o[3] = f2b(v.w);
    *(bf16x4*)(dst + i) = o;
    return;
  }
  const int bx = blockIdx.x;
  if (bx >= 256) return;
  const int wj = bx >> 6, rem = bx & 63;
  const float* W = wj == 0 ? W0 : wj == 1 ? W1 : wj == 2 ? W2 : W3;
  short* T = wj == 0 ? T0 : wj == 1 ? T1 : wj == 2 ? T2 : T3;
  __shared__ float tile[64][65];
  const int k0 = (rem >> 3) * 64, n0 = (rem & 7) * 64;
#pragma unroll
  for (int i = 0; i < 4; ++i) {
    int r = (t >> 4) + i * 16;
    int c = (t & 15) * 4;
    float4 v = *(const float4*)&W[(size_t)(k0 + r) * ND + n0 + c];
    tile[r][c] = v.x; tile[r][c + 1] = v.y;
    tile[r][c + 2] = v.z; tile[r][c + 3] = v.w;
  }
  __syncthreads();
#pragma unroll
  for (int i = 0; i < 4; ++i) {
    int n = (t >> 4) + i * 16;
    int kc = (t & 15) * 4;
    bf16x4 o;
#pragma unroll
    for (int j = 0; j < 4; ++j) o[j] = f2b(tile[kc + j][n]);
    *(bf16x4*)&T[(size_t)(n0 + n) * ND + k0 + kc] = o;
  }
}

// ---------------------------------------------------------------------------
// QKV GEMM: 128x128 tile, 4 waves each 64x64 (acc 4x4), BK=64, single-buffer
// DMA staging (m97 2-barrier), XOR-swizzled LDS (pitch 64, chunk ^= row&7).
// mode 1: bf16 row-major out; 2: bf16 V^T out via LDS-transposed coalesced
// epilogue.
// ---------------------------------------------------------------------------
__device__ __forceinline__ void gemm128(const short* __restrict__ A,
                                        const short* __restrict__ Bt,
                                        short* __restrict__ Cout, int mode,
                                        float alpha) {
  __shared__ short As[128 * 64];
  __shared__ short Bs[128 * 64];
  __shared__ short Tb[64 * 128];  // mode-2 transpose staging [c][r], 16 KB
  const int t = threadIdx.x;
  const int wave = t >> 6, lane = t & 63;
  const int m = lane & 15, quad = lane >> 4;
  const int m0 = blockIdx.y * 128, n0 = blockIdx.x * 128;
  const int mh = (wave >> 1) * 64, nh = (wave & 1) * 64;
  const int r8 = lane >> 3;        // 0..7: row within wave's staging band
  const int c8 = (lane & 7) ^ r8;  // swizzled global chunk for this lane
  const int mx7 = m & 7;           // fragment-read swizzle key
  f32x4 acc[4][4];
#pragma unroll
  for (int i = 0; i < 4; ++i)
#pragma unroll
    for (int j = 0; j < 4; ++j) acc[i][j] = (f32x4){0.f, 0.f, 0.f, 0.f};

  for (int k0 = 0; k0 < ND; k0 += 64) {
    __syncthreads();  // prior iteration's fragment readers done
#pragma unroll
    for (int i = 0; i < 4; ++i) {
      int row = i * 32 + wave * 8 + r8;
      dma16(A + (size_t)(m0 + row) * ND + k0 + c8 * 8,
            As + (i * 256 + wave * 64) * 8);
      dma16(Bt + (size_t)(n0 + row) * ND + k0 + c8 * 8,
            Bs + (i * 256 + wave * 64) * 8);
    }
    __syncthreads();  // drains vmcnt: all DMA visible
    bf16x8 af[4][2], bf[4][2];
#pragma unroll
    for (int mt = 0; mt < 4; ++mt)
#pragma unroll
      for (int kc = 0; kc < 2; ++kc)
        af[mt][kc] = *(const bf16x8*)(As + (mh + mt * 16 + m) * 64 +
                                      ((kc * 4 + quad) ^ mx7) * 8);
#pragma unroll
    for (int nt = 0; nt < 4; ++nt)
#pragma unroll
      for (int kc = 0; kc < 2; ++kc)
        bf[nt][kc] = *(const bf16x8*)(Bs + (nh + nt * 16 + m) * 64 +
                                      ((kc * 4 + quad) ^ mx7) * 8);
#pragma unroll
    for (int mt = 0; mt < 4; ++mt)
#pragma unroll
      for (int nt = 0; nt < 4; ++nt)
#pragma unroll
        for (int kc = 0; kc < 2; ++kc)
          acc[mt][nt] = __builtin_amdgcn_mfma_f32_16x16x32_bf16(
              af[mt][kc], bf[nt][kc], acc[mt][nt], 0, 0, 0);
  }
  if (mode == 2) {
    // V^T epilogue: two 64-col passes through Tb[c][r], then each thread
    // writes 64 B of s-contiguous V^T (256 B contiguous per channel row).
    const int h0 = n0 >> 6;                        // n0 is 128-aligned
    const int b_ = m0 >> 11, s0g = m0 & (NS - 1);  // 128-row tile: one b
#pragma unroll
    for (int p = 0; p < 2; ++p) {
      __syncthreads();  // Tb free (p0: main loop done; p1: p0 readers done)
      if ((wave & 1) == p) {
        // wave's cols nh + nt*16 + m, nh == p*64 -> local c = nt*16 + m
#pragma unroll
        for (int mt = 0; mt < 4; ++mt)
#pragma unroll
          for (int nt = 0; nt < 4; ++nt)
#pragma unroll
            for (int r = 0; r < 4; ++r)
              Tb[(nt * 16 + m) * 128 + mh + mt * 16 + quad * 4 + r] =
                  f2b(acc[mt][nt][r] * alpha);
      }
      __syncthreads();
      {
        int c = t >> 2, sc = (t & 3) * 32;  // c: 0..63, sc: 0/32/64/96
        int gcol = p * 64 + c;
        int h_ = h0 + (gcol >> 6), d_ = gcol & (DEP - 1);
        short* dst =
            Cout + (size_t)((b_ * NH + h_) * DEP + d_) * NS + s0g + sc;
        const short* src = Tb + c * 128 + sc;
#pragma unroll
        for (int i = 0; i < 4; ++i)
          *(bf16x8*)(dst + i * 8) = *(const bf16x8*)(src + i * 8);
      }
    }
  } else {
#pragma unroll
    for (int mt = 0; mt < 4; ++mt)
#pragma unroll
      for (int nt = 0; nt < 4; ++nt)
#pragma unroll
        for (int r = 0; r < 4; ++r) {
          int row = m0 + mh + mt * 16 + quad * 4 + r;
          int col = n0 + nh + nt * 16 + m;
          Cout[(size_t)row * ND + col] = f2b(acc[mt][nt][r] * alpha);
        }
  }
}

__global__ __launch_bounds__(256) void qkv_gemm(
    const short* __restrict__ xb, const short* __restrict__ yb,
    const short* __restrict__ Wqt, const short* __restrict__ Wkt,
    const short* __restrict__ Wvt, short* __restrict__ Qb,
    short* __restrict__ Kb, short* __restrict__ Vtb) {
  if (blockIdx.z == 0)
    gemm128(xb, Wqt, Qb, 1, QSCALE);  // scale + log2e folded into Q
  else if (blockIdx.z == 1)
    gemm128(yb, Wkt, Kb, 1, 1.0f);
  else
    gemm128(yb, Wvt, Vtb, 2, 1.0f);
}

// ---------------------------------------------------------------------------
// Output GEMM: 128x64 tile, BK=64, double-buffered DMA, swizzled LDS,
// fp32 row-major out.  Grid 512 = 2 blocks/CU.
// ---------------------------------------------------------------------------
__global__ __launch_bounds__(256) void out_gemm(const short* __restrict__ A,
                                                const short* __restrict__ Bt,
                                                float* __restrict__ Cout) {
  __shared__ short As[2][128 * 64];
  __shared__ short Bs[2][64 * 64];
  const int t = threadIdx.x;
  const int wave = t >> 6, lane = t & 63;
  const int m = lane & 15, quad = lane >> 4;
  const int m0 = blockIdx.y * 128, n0 = blockIdx.x * 64;
  const int mh = (wave >> 1) * 64, nh = (wave & 1) * 32;
  const int r8 = lane >> 3;
  const int c8 = (lane & 7) ^ r8;
  const int mx7 = m & 7;
  f32x4 acc[4][2];
#pragma unroll
  for (int i = 0; i < 4; ++i)
#pragma unroll
    for (int j = 0; j < 2; ++j) acc[i][j] = (f32x4){0.f, 0.f, 0.f, 0.f};

#pragma unroll
  for (int i = 0; i < 4; ++i)
    dma16(A + (size_t)(m0 + i * 32 + wave * 8 + r8) * ND + c8 * 8,
          As[0] + (i * 256 + wave * 64) * 8);
#pragma unroll
  for (int i = 0; i < 2; ++i)
    dma16(Bt + (size_t)(n0 + i * 32 + wave * 8 + r8) * ND + c8 * 8,
          Bs[0] + (i * 256 + wave * 64) * 8);

  int buf = 0;
  for (int k0 = 0; k0 < ND; k0 += 64, buf ^= 1) {
    __syncthreads();
    if (k0 + 64 < ND) {
#pragma unroll
      for (int i = 0; i < 4; ++i)
        dma16(A + (size_t)(m0 + i * 32 + wave * 8 + r8) * ND + k0 + 64 + c8 * 8,
              As[buf ^ 1] + (i * 256 + wave * 64) * 8);
#pragma unroll
      for (int i = 0; i < 2; ++i)
        dma16(Bt + (size_t)(n0 + i * 32 + wave * 8 + r8) * ND + k0 + 64 +
                  c8 * 8,
              Bs[buf ^ 1] + (i * 256 + wave * 64) * 8);
    }
    bf16x8 af[4][2], bf[2][2];
#pragma unroll
    for (int mt = 0; mt < 4; ++mt)
#pragma unroll
      for (int kc = 0; kc < 2; ++kc)
        af[mt][kc] = *(const bf16x8*)(As[buf] + (mh + mt * 16 + m) * 64 +
                                      ((kc * 4 + quad) ^ mx7) * 8);
#pragma unroll
    for (int nt = 0; nt < 2; ++nt)
#pragma unroll
      for (int kc = 0; kc < 2; ++kc)
        bf[nt][kc] = *(const bf16x8*)(Bs[buf] + (nh + nt * 16 + m) * 64 +
                                      ((kc * 4 + quad) ^ mx7) * 8);
#pragma unroll
    for (int mt = 0; mt < 4; ++mt)
#pragma unroll
      for (int nt = 0; nt < 2; ++nt)
#pragma unroll
        for (int kc = 0; kc < 2; ++kc)
          acc[mt][nt] = __builtin_amdgcn_mfma_f32_16x16x32_bf16(
              af[mt][kc], bf[nt][kc], acc[mt][nt], 0, 0, 0);
  }
#pragma unroll
  for (int mt = 0; mt < 4; ++mt)
#pragma unroll
    for (int nt = 0; nt < 2; ++nt)
#pragma unroll
      for (int r = 0; r < 4; ++r) {
        int row = m0 + mh + mt * 16 + quad * 4 + r;
        int col = n0 + nh + nt * 16 + m;
        Cout[(size_t)row * ND + col] = acc[mt][nt][r];
      }
}

// ---------------------------------------------------------------------------
// Flash attention, S^T formulation, 32x32x16 MFMA, in-register softmax,
// IN-BLOCK kv-split x2 (8 waves: 0-3 kv[0,1024), 4-7 kv[1024,2048)).
// SINGLE-BUFFERED K/V (m97 2-barrier): 32 KB LDS -> 4 blocks/CU = 32
// waves/CU (was 64 KB dbuf -> 2 blocks/CU).  The dbuf's cross-barrier
// prefetch is traded for 2x wave-level TLP: with 4 resident blocks, other
// blocks' compute covers each block's exposed staging latency (m114/m97
// implicit-overlap regime).  This kernel's proven lever is occupancy
// (r1->r3: 18->32% = -17%); all in-wave ILP schemes (r4-r6) regressed.
// Max-free softmax partials combine exactly in LDS: O=(O0+O1)/(l0+l1).
// ---------------------------------------------------------------------------
__global__ __launch_bounds__(512, 4) void attn_mfma(
    const short* __restrict__ Qb, const short* __restrict__ Kb,
    const short* __restrict__ Vtb, short* __restrict__ Ob) {
  __shared__ short KVs[2][2][64 * 64];  // [K=0/V=1][zh][kv/d tile], 32 KB
  __shared__ float lxs[128];            // cross-half l exchange
  const int t = threadIdx.x;
  const int wave = t >> 6, lane = t & 63;
  const int zh = wave >> 2, wl = wave & 3;  // kv-half, q-subtile
  const int l31 = lane & 31, hi = lane >> 5;
  const int sw = lane & 7;  // fragment-read swizzle key (row&7 == lane&7)
  const int bh = blockIdx.y, b = bh >> 3, h = bh & 7;
  const int q0 = blockIdx.x * 128 + wl * 32;
  const int kvb = zh * KVHALF;
  const size_t rowb = (size_t)b * NS;
  const short* Vtbase = Vtb + (size_t)(bh * DEP) * NS;
  const int r8 = lane >> 3;
  const int c8 = (lane & 7) ^ r8;
  short* Ksb = &KVs[0][zh][0];
  short* Vsb = &KVs[1][zh][0];

  // Q fragments (B-operand): col=q=l31, k(d) = dc*16 + hi*8 + j
  bf16x8 qf[4];
#pragma unroll
  for (int dc = 0; dc < 4; ++dc)
    qf[dc] = *(const bf16x8*)(Qb + (rowb + q0 + l31) * ND + h * DEP + dc * 16 +
                              hi * 8);

  // loop-invariant zero C-operand: avoids 32 v_mov per iteration (St init)
  f32x16 kzero;
#pragma unroll
  for (int i = 0; i < 16; ++i) kzero[i] = 0.f;

  float l_ = 0.0f;
  f32x16 Ot[2];
#pragma unroll
  for (int dt = 0; dt < 2; ++dt)
#pragma unroll
    for (int i = 0; i < 16; ++i) Ot[dt][i] = 0.f;

  for (int kv0 = 0; kv0 < KVHALF; kv0 += 64) {
    __syncthreads();  // prior iteration's fragment readers done
#pragma unroll
    for (int i = 0; i < 2; ++i) {
      int row = i * 32 + wl * 8 + r8;
      dma16(Kb + (rowb + kvb + kv0 + row) * ND + h * DEP + c8 * 8,
            Ksb + (i * 256 + wl * 64) * 8);
      dma16(Vtbase + (size_t)row * NS + kvb + kv0 + c8 * 8,
            Vsb + (i * 256 + wl * 64) * 8);
    }
    __syncthreads();  // drains vmcnt: K/V tiles visible

    // QK^T: St[kt] = S^T tile (kv = kt*32+row, q = col = l31)
    f32x16 St[2];
#pragma unroll
    for (int kt = 0; kt < 2; ++kt) {
      bf16x8 kf0 = *(const bf16x8*)(Ksb + (kt * 32 + l31) * 64 +
                                    (hi ^ sw) * 8);
      St[kt] = __builtin_amdgcn_mfma_f32_32x32x16_bf16(kf0, qf[0], kzero,
                                                       0, 0, 0);
#pragma unroll
      for (int dc = 1; dc < 4; ++dc) {
        bf16x8 kf = *(const bf16x8*)(Ksb + (kt * 32 + l31) * 64 +
                                     ((dc * 2 + hi) ^ sw) * 8);
        St[kt] = __builtin_amdgcn_mfma_f32_32x32x16_bf16(kf, qf[dc], St[kt],
                                                         0, 0, 0);
      }
    }

    // softmax (max-free, exp2) + in-register P^T -> B-fragment assembly.
    // St reg r (tile kt): kv = kt*32 + (r&3) + 8*(r>>2) + 4*hi.
    // B-frag slice s needs: elem j = P[kv0 + s*16 + hi*8 + j][q].
    bf16x8 pf[4];
    float rs = 0.f;
#pragma unroll
    for (int s = 0; s < 4; ++s) {
      const int kt = s >> 1, base = (s & 1) * 8;
      float E[8];
#pragma unroll
      for (int j = 0; j < 8; ++j) {
        E[j] = __builtin_amdgcn_exp2f(St[kt][base + j]);
      }
      rs += ((E[0] + E[1]) + (E[2] + E[3])) + ((E[4] + E[5]) + (E[6] + E[7]));
      unsigned A0 = pk2(E[0], E[1]), A1 = pk2(E[2], E[3]);
      unsigned A2 = pk2(E[4], E[5]), A3 = pk2(E[6], E[7]);
      // swap: out0 = [a.lo | b.lo], out1 = [a.hi | b.hi]
      auto r02 =
          __builtin_amdgcn_permlane32_swap((int)A0, (int)A2, false, false);
      auto r13 =
          __builtin_amdgcn_permlane32_swap((int)A1, (int)A3, false, false);
      union { bf16x8 v; int u[4]; } pu;
      pu.u[0] = r02[0]; pu.u[1] = r13[0]; pu.u[2] = r02[1]; pu.u[3] = r13[1];
      pf[s] = pu.v;
    }
    l_ += rs;

    // PV: Ot^T[dt] += V^T[d, kv-slice] * P^T[kv-slice, q]
#pragma unroll
    for (int dt = 0; dt < 2; ++dt)
#pragma unroll
      for (int s = 0; s < 4; ++s) {
        bf16x8 vf = *(const bf16x8*)(Vsb + (dt * 32 + l31) * 64 +
                                     ((s * 2 + hi) ^ sw) * 8);
        Ot[dt] = __builtin_amdgcn_mfma_f32_32x32x16_bf16(vf, pf[s], Ot[dt],
                                                         0, 0, 0);
      }
  }

  // per-wave denominator partial: lane l and l^32 hold complementary kv sets
  l_ += __shfl_xor(l_, 32, 64);

  // cross-half combine in LDS (aliased over dead K/V staging buffers).
  __syncthreads();  // all K/V fragment reads of the last tile complete
  float* Ox = (float*)KVs;  // [4][64][32] fp32 = 32 KB (spans KVs exactly)
  if (zh == 1) {
#pragma unroll
    for (int dt = 0; dt < 2; ++dt)
#pragma unroll
      for (int r = 0; r < 16; ++r) {
        int d = dt * 32 + (r & 3) + 8 * (r >> 2) + 4 * hi;
        Ox[(wl * 64 + d) * 32 + l31] = Ot[dt][r];
      }
    if (lane < 32) lxs[wl * 32 + l31] = l_;
  }
  __syncthreads();
  if (zh == 0) {
    float linv = 1.0f / (l_ + lxs[wl * 32 + l31]);
    size_t row = rowb + q0 + l31;
    // Ot reg r (tile dt): d = dt*32 + (r&3) + 8*(r>>2) + 4*hi -> 8B stores
#pragma unroll
    for (int dt = 0; dt < 2; ++dt)
#pragma unroll
      for (int g = 0; g < 4; ++g) {
        int d0 = dt * 32 + g * 8 + hi * 4;
        float o[4];
#pragma unroll
        for (int j = 0; j < 4; ++j)
          o[j] = Ot[dt][g * 4 + j] + Ox[(wl * 64 + d0 + j) * 32 + l31];
        uint2 pk;
        pk.x = pk2(o[0] * linv, o[1] * linv);
        pk.y = pk2(o[2] * linv, o[3] * linv);
        *(uint2*)(Ob + row * ND + h * DEP + d0) = pk;
      }
  }
}

// ---------------------------------------------------------------------------
extern "C" void kernel_launch(void* const* d_in, const int* in_sizes, int n_in,
                              void* d_out, int out_size, void* d_ws,
                              size_t ws_size, hipStream_t stream) {
  const float* x = (const float*)d_in[0];
  const float* y = (const float*)d_in[1];
  const float* Wq = (const float*)d_in[2];
  const float* Wk = (const float*)d_in[3];
  const float* Wv = (const float*)d_in[4];
  const float* Wo = (const float*)d_in[5];
  float* out = (float*)d_out;

  const size_t mat = (size_t)NB * NS * ND;
  const size_t wsz = (size_t)ND * ND;
  short* xb = (short*)d_ws;
  short* yb = xb + mat;
  short* Wqt = yb + mat;
  short* Wkt = Wqt + wsz;
  short* Wvt = Wkt + wsz;
  short* Wot = Wvt + wsz;
  short* Qb = Wot + wsz;
  short* Kb = Qb + mat;
  short* Vtb = Kb + mat;
  short* attnb = xb;  // reuse: xb dead after QKV GEMM

  prep<<<dim3(mat / 1024, 3), 256, 0, stream>>>(x, y, Wq, Wk, Wv, Wo, xb, yb,
                                                Wqt, Wkt, Wvt, Wot);
  qkv_gemm<<<dim3(ND / 128, (NB * NS) / 128, 3), 256, 0, stream>>>(
      xb, yb, Wqt, Wkt, Wvt, Qb, Kb, Vtb);
  attn_mfma<<<dim3(NS / 128, NB * NH), 512, 0, stream>>>(Qb, Kb, Vtb, attnb);
  out_gemm<<<dim3(ND / 64, (NB * NS) / 128), 256, 0, stream>>>(attnb, Wot,
                                                               out);
}